// Round 1
// baseline (612.694 us; speedup 1.0000x reference)
//
#include <hip/hip_runtime.h>
#include <hip/hip_bf16.h>

typedef unsigned short u16;
typedef short bf16x8 __attribute__((ext_vector_type(8)));
typedef float f32x4 __attribute__((ext_vector_type(4)));

#define DM     1024
#define SEQ    4096
#define NBATCH 4
#define NWIN   31

__device__ __forceinline__ u16 f2b(float f) {
  union { float f; unsigned u; } x; x.f = f;
  unsigned r = (x.u + 0x7fffu + ((x.u >> 16) & 1u)) >> 16;  // RNE
  return (u16)r;
}

// ---------------- fp32 -> bf16 convert (x4 vectorized) ----------------
__global__ __launch_bounds__(256) void k_convert(const float* __restrict__ in,
                                                 u16* __restrict__ out, int n4) {
  int i = blockIdx.x * 256 + threadIdx.x;
  if (i >= n4) return;
  float4 v = ((const float4*)in)[i];
  ushort4 o; o.x = f2b(v.x); o.y = f2b(v.y); o.z = f2b(v.z); o.w = f2b(v.w);
  ((ushort4*)out)[i] = o;
}

// ---------------- W (K x N fp32) -> Wt (N x K bf16) ----------------
__global__ __launch_bounds__(256) void k_transpose(const float* __restrict__ W,
                                                   u16* __restrict__ Wt) {
  __shared__ float tile[32][33];
  int n0 = blockIdx.x * 32, k0 = blockIdx.y * 32;
  int tx = threadIdx.x, ty = threadIdx.y;
  #pragma unroll
  for (int i = ty; i < 32; i += 8) tile[i][tx] = W[(size_t)(k0 + i) * DM + n0 + tx];
  __syncthreads();
  #pragma unroll
  for (int i = ty; i < 32; i += 8) Wt[(size_t)(n0 + i) * DM + k0 + tx] = f2b(tile[tx][i]);
}

// ---------------- bf16 MFMA GEMM: C[M,N] = A[M,K] * Bt[N,K]^T + bias ----------------
// 128x128 block tile, 4 waves each 64x64 (4x4 of 16x16x32 MFMA), BK=32.
__global__ __launch_bounds__(256) void k_gemm(const u16* __restrict__ A, const u16* __restrict__ Bt,
                                              const float* __restrict__ bias,
                                              float* __restrict__ Cf, u16* __restrict__ Cb,
                                              int M, int N, int K) {
  __shared__ u16 As[128 * 40];  // row stride 40 (pad 8) -> conflict-free b128 frag reads
  __shared__ u16 Bs[128 * 40];
  const int tid = threadIdx.x;
  const int wv = tid >> 6, lane = tid & 63;
  const int quad = lane >> 4, l16 = lane & 15;
  const int m0 = blockIdx.y * 128, n0 = blockIdx.x * 128;
  const int wm = (wv >> 1) * 64, wn = (wv & 1) * 64;
  f32x4 acc[4][4];
  #pragma unroll
  for (int a = 0; a < 4; ++a)
    #pragma unroll
    for (int b = 0; b < 4; ++b) acc[a][b] = (f32x4){0.f, 0.f, 0.f, 0.f};

  for (int kk = 0; kk < K; kk += 32) {
    #pragma unroll
    for (int i = 0; i < 4; ++i) {
      int c = i * 256 + tid;            // 0..511 A chunks, 512..1023 B chunks
      int row = (c >> 2) & 127;
      int coff = (c & 3) * 8;
      const u16* src = (c < 512) ? (A + (size_t)(m0 + row) * K + kk + coff)
                                 : (Bt + (size_t)(n0 + row) * K + kk + coff);
      u16* dst = ((c < 512) ? As : Bs) + row * 40 + coff;
      *(uint4*)dst = *(const uint4*)src;
    }
    __syncthreads();
    bf16x8 af[4], bf[4];
    #pragma unroll
    for (int t = 0; t < 4; ++t) af[t] = *(const bf16x8*)&As[(wm + t * 16 + l16) * 40 + quad * 8];
    #pragma unroll
    for (int t = 0; t < 4; ++t) bf[t] = *(const bf16x8*)&Bs[(wn + t * 16 + l16) * 40 + quad * 8];
    #pragma unroll
    for (int mt = 0; mt < 4; ++mt)
      #pragma unroll
      for (int nt = 0; nt < 4; ++nt)
        acc[mt][nt] = __builtin_amdgcn_mfma_f32_16x16x32_bf16(af[mt], bf[nt], acc[mt][nt], 0, 0, 0);
    __syncthreads();
  }
  #pragma unroll
  for (int mt = 0; mt < 4; ++mt) {
    #pragma unroll
    for (int nt = 0; nt < 4; ++nt) {
      int row = m0 + wm + mt * 16 + quad * 4;   // D layout: row=(lane>>4)*4+reg
      int col = n0 + wn + nt * 16 + l16;        //           col=lane&15
      float bv = bias[col];
      #pragma unroll
      for (int r = 0; r < 4; ++r) {
        float v = acc[mt][nt][r] + bv;
        if (Cf) Cf[(size_t)(row + r) * N + col] = v;
        else    Cb[(size_t)(row + r) * N + col] = f2b(v);
      }
    }
  }
}

// ---------------- windowed attention ----------------
// grid (4 q-subtiles, 31 windows, 4 batches); block 256 = 4 waves.
// Phase 1: S = Q*K^T/8 (wave wv owns query rows [wv*16,wv*16+16), all 256 keys -> in-register softmax)
// Phase 2: O = P*V, N tiled in 4 slabs of 256; atomicAdd fp32 to accum.
#define PSTR 264
#define VSTR 258
__global__ __launch_bounds__(256) void k_attn(const u16* __restrict__ Qb, const u16* __restrict__ Kb,
                                              const u16* __restrict__ Vb, float* __restrict__ accum) {
  __shared__ u16 stage[12800];       // Qs(64*40) + Ks(256*40); reused as Vs(32*258)
  __shared__ u16 Pbuf[64 * PSTR];
  u16* Qs = stage;
  u16* Ks = stage + 2560;
  u16* Vs = stage;

  const int tid = threadIdx.x;
  const int wv = tid >> 6, lane = tid & 63;
  const int quad = lane >> 4, l16 = lane & 15;
  const int qt = blockIdx.x, w = blockIdx.y, b = blockIdx.z;
  const int s0 = w * 128;
  const size_t base = (size_t)b * SEQ * DM;
  const int qrow0 = s0 + qt * 64;

  f32x4 acc[16];
  #pragma unroll
  for (int i = 0; i < 16; ++i) acc[i] = (f32x4){0.f, 0.f, 0.f, 0.f};

  // ---- phase 1: scores ----
  for (int kk = 0; kk < DM; kk += 32) {
    #pragma unroll
    for (int i = 0; i < 5; ++i) {
      int c = i * 256 + tid;          // 0..255 Q chunks, 256..1279 K chunks
      if (c < 256) {
        int row = c >> 2, coff = (c & 3) * 8;
        *(uint4*)&Qs[row * 40 + coff] =
            *(const uint4*)&Qb[base + (size_t)(qrow0 + row) * DM + kk + coff];
      } else {
        int d = c - 256;
        int row = d >> 2, coff = (d & 3) * 8;
        *(uint4*)&Ks[row * 40 + coff] =
            *(const uint4*)&Kb[base + (size_t)(s0 + row) * DM + kk + coff];
      }
    }
    __syncthreads();
    bf16x8 aq = *(const bf16x8*)&Qs[(wv * 16 + l16) * 40 + quad * 8];
    #pragma unroll
    for (int nt = 0; nt < 16; ++nt) {
      bf16x8 bk = *(const bf16x8*)&Ks[(nt * 16 + l16) * 40 + quad * 8];
      acc[nt] = __builtin_amdgcn_mfma_f32_16x16x32_bf16(aq, bk, acc[nt], 0, 0, 0);
    }
    __syncthreads();
  }

  // ---- softmax over keys (row r lives in the 16 lanes of this quad, reg r&3) ----
  float mx[4] = {-1e30f, -1e30f, -1e30f, -1e30f};
  float sm[4] = {0.f, 0.f, 0.f, 0.f};
  #pragma unroll
  for (int nt = 0; nt < 16; ++nt)
    #pragma unroll
    for (int r = 0; r < 4; ++r) {
      float s = acc[nt][r] * 0.125f;
      acc[nt][r] = s;
      mx[r] = fmaxf(mx[r], s);
    }
  #pragma unroll
  for (int r = 0; r < 4; ++r)
    #pragma unroll
    for (int off = 8; off > 0; off >>= 1)
      mx[r] = fmaxf(mx[r], __shfl_xor(mx[r], off, 64));
  #pragma unroll
  for (int nt = 0; nt < 16; ++nt)
    #pragma unroll
    for (int r = 0; r < 4; ++r) {
      float e = __expf(acc[nt][r] - mx[r]);
      acc[nt][r] = e;
      sm[r] += e;
    }
  #pragma unroll
  for (int r = 0; r < 4; ++r)
    #pragma unroll
    for (int off = 8; off > 0; off >>= 1)
      sm[r] += __shfl_xor(sm[r], off, 64);
  float inv[4];
  #pragma unroll
  for (int r = 0; r < 4; ++r) inv[r] = 1.f / sm[r];
  #pragma unroll
  for (int nt = 0; nt < 16; ++nt)
    #pragma unroll
    for (int r = 0; r < 4; ++r)
      Pbuf[(wv * 16 + quad * 4 + r) * PSTR + nt * 16 + l16] = f2b(acc[nt][r] * inv[r]);
  __syncthreads();

  // ---- phase 2: O = P * V ----
  for (int slab = 0; slab < 4; ++slab) {
    const int nbase = slab * 256;
    f32x4 acc2[4][4];
    #pragma unroll
    for (int a = 0; a < 4; ++a)
      #pragma unroll
      for (int c = 0; c < 4; ++c) acc2[a][c] = (f32x4){0.f, 0.f, 0.f, 0.f};
    for (int ks = 0; ks < 8; ++ks) {
      #pragma unroll
      for (int i = 0; i < 4; ++i) {
        int c = i * 256 + tid;
        int kr = c >> 5, nc8 = (c & 31) * 8;
        uint4 v = *(const uint4*)&Vb[base + (size_t)(s0 + ks * 32 + kr) * DM + nbase + nc8];
        uint* dp = (uint*)&Vs[kr * VSTR + nc8];   // VSTR=258: b32-aligned, conflict-free reads
        dp[0] = v.x; dp[1] = v.y; dp[2] = v.z; dp[3] = v.w;
      }
      __syncthreads();
      bf16x8 af[4];
      #pragma unroll
      for (int mt = 0; mt < 4; ++mt)
        af[mt] = *(const bf16x8*)&Pbuf[(mt * 16 + l16) * PSTR + ks * 32 + quad * 8];
      #pragma unroll
      for (int u = 0; u < 4; ++u) {
        union { u16 s[8]; bf16x8 v; } bb;
        int ncol = (wv * 4 + u) * 16 + l16;
        #pragma unroll
        for (int j = 0; j < 8; ++j) bb.s[j] = Vs[(quad * 8 + j) * VSTR + ncol];
        #pragma unroll
        for (int mt = 0; mt < 4; ++mt)
          acc2[mt][u] = __builtin_amdgcn_mfma_f32_16x16x32_bf16(af[mt], bb.v, acc2[mt][u], 0, 0, 0);
      }
      __syncthreads();
    }
    #pragma unroll
    for (int mt = 0; mt < 4; ++mt)
      #pragma unroll
      for (int u = 0; u < 4; ++u) {
        int row = qrow0 + mt * 16 + quad * 4;
        int col = nbase + (wv * 4 + u) * 16 + l16;
        #pragma unroll
        for (int r = 0; r < 4; ++r)
          atomicAdd(&accum[base + (size_t)(row + r) * DM + col], acc2[mt][u][r]);
      }
  }
}

// ---------------- accum / counts -> bf16 ----------------
__global__ __launch_bounds__(256) void k_norm(const float* __restrict__ acc,
                                              u16* __restrict__ out, int n4) {
  int i = blockIdx.x * 256 + threadIdx.x;
  if (i >= n4) return;
  int s = (i >> 8) & (SEQ - 1);                 // i*4/1024 mod 4096
  int lo = (s - 128) >> 7; if (lo < 0) lo = 0;  // ceil((s-255)/128)
  int hi = s >> 7; if (hi > NWIN - 1) hi = NWIN - 1;
  float invc = 1.0f / (float)(hi - lo + 1);
  float4 v = ((const float4*)acc)[i];
  ushort4 o;
  o.x = f2b(v.x * invc); o.y = f2b(v.y * invc);
  o.z = f2b(v.z * invc); o.w = f2b(v.w * invc);
  ((ushort4*)out)[i] = o;
}

extern "C" void kernel_launch(void* const* d_in, const int* in_sizes, int n_in,
                              void* d_out, int out_size, void* d_ws, size_t ws_size,
                              hipStream_t stream) {
  const float* x  = (const float*)d_in[0];
  const float* Wq = (const float*)d_in[1];
  const float* bq = (const float*)d_in[2];
  const float* Wk = (const float*)d_in[3];
  const float* bk = (const float*)d_in[4];
  const float* Wv = (const float*)d_in[5];
  const float* bv = (const float*)d_in[6];
  const float* Wo = (const float*)d_in[7];
  const float* bo = (const float*)d_in[8];
  float* out = (float*)d_out;

  char* ws = (char*)d_ws;
  const size_t NTOK = (size_t)NBATCH * SEQ;   // 16384
  const size_t XB   = NTOK * DM * 2;          // 32 MB per bf16 activation buffer
  u16* xb  = (u16*)(ws);                      // x bf16; later reused for attn output bf16
  u16* qb  = (u16*)(ws + XB);
  u16* kb  = (u16*)(ws + 2 * XB);
  u16* vb  = (u16*)(ws + 3 * XB);
  u16* wqt = (u16*)(ws + 4 * XB);
  u16* wkt = wqt + (size_t)DM * DM;
  u16* wvt = wkt + (size_t)DM * DM;
  u16* wot = wvt + (size_t)DM * DM;
  float* accum = (float*)(ws + 4 * XB + 4 * (size_t)DM * DM * 2);
  // total workspace use: 4*32MB + 8MB + 64MB = 200 MB

  int n4tok = (int)(NTOK * DM / 4);
  k_convert<<<(n4tok + 255) / 256, 256, 0, stream>>>(x, xb, n4tok);
  dim3 tpb(32, 8);
  dim3 tgr(DM / 32, DM / 32);
  k_transpose<<<tgr, tpb, 0, stream>>>(Wq, wqt);
  k_transpose<<<tgr, tpb, 0, stream>>>(Wk, wkt);
  k_transpose<<<tgr, tpb, 0, stream>>>(Wv, wvt);
  k_transpose<<<tgr, tpb, 0, stream>>>(Wo, wot);

  dim3 ggr(DM / 128, NTOK / 128);  // (8,128)
  k_gemm<<<ggr, 256, 0, stream>>>(xb, wqt, bq, nullptr, qb, (int)NTOK, DM, DM);
  k_gemm<<<ggr, 256, 0, stream>>>(xb, wkt, bk, nullptr, kb, (int)NTOK, DM, DM);
  k_gemm<<<ggr, 256, 0, stream>>>(xb, wvt, bv, nullptr, vb, (int)NTOK, DM, DM);

  hipMemsetAsync(accum, 0, NTOK * DM * 4, stream);
  k_attn<<<dim3(4, NWIN, NBATCH), 256, 0, stream>>>(qb, kb, vb, accum);
  k_norm<<<(n4tok + 255) / 256, 256, 0, stream>>>(accum, xb, n4tok);
  k_gemm<<<ggr, 256, 0, stream>>>(xb, wot, bo, out, nullptr, (int)NTOK, DM, DM);
}

// Round 2
// 522.297 us; speedup vs baseline: 1.1731x; 1.1731x over previous
//
#include <hip/hip_runtime.h>
#include <hip/hip_bf16.h>

typedef unsigned short u16;
typedef short bf16x8 __attribute__((ext_vector_type(8)));
typedef float f32x4 __attribute__((ext_vector_type(4)));

#define DM     1024
#define SEQ    4096
#define NBATCH 4
#define NWIN   31
#define NTOK   16384   // NBATCH*SEQ

__device__ __forceinline__ u16 f2b(float f) {
  union { float f; unsigned u; } x; x.f = f;
  unsigned r = (x.u + 0x7fffu + ((x.u >> 16) & 1u)) >> 16;  // RNE
  return (u16)r;
}
__device__ __forceinline__ float b2f(u16 v) {
  union { unsigned u; float f; } x; x.u = ((unsigned)v) << 16; return x.f;
}
// async global->LDS, 16B per lane. lds dest must be wave-uniform base (+lane*16).
__device__ __forceinline__ void gload_lds16(const u16* g, u16* l) {
  __builtin_amdgcn_global_load_lds(
      (const __attribute__((address_space(1))) void*)g,
      (__attribute__((address_space(3))) void*)l, 16, 0, 0);
}

// ---------------- fp32 -> bf16 convert (x4 vectorized) ----------------
__global__ __launch_bounds__(256) void k_convert(const float* __restrict__ in,
                                                 u16* __restrict__ out, int n4) {
  int i = blockIdx.x * 256 + threadIdx.x;
  if (i >= n4) return;
  float4 v = ((const float4*)in)[i];
  ushort4 o; o.x = f2b(v.x); o.y = f2b(v.y); o.z = f2b(v.z); o.w = f2b(v.w);
  ((ushort4*)out)[i] = o;
}

// ---------------- W (K x N fp32) -> Wt (N x K bf16) ----------------
__global__ __launch_bounds__(256) void k_transpose(const float* __restrict__ W,
                                                   u16* __restrict__ Wt) {
  __shared__ float tile[32][33];
  int n0 = blockIdx.x * 32, k0 = blockIdx.y * 32;
  int tx = threadIdx.x, ty = threadIdx.y;
  #pragma unroll
  for (int i = ty; i < 32; i += 8) tile[i][tx] = W[(size_t)(k0 + i) * DM + n0 + tx];
  __syncthreads();
  #pragma unroll
  for (int i = ty; i < 32; i += 8) Wt[(size_t)(n0 + i) * DM + k0 + tx] = f2b(tile[tx][i]);
}

// ---------------- bf16 MFMA GEMM: C[M,N] = A[M,K] * Bt[N,K]^T + bias ----------------
// 128x128 tile, 4 waves each 64x64, BK=32, async global_load_lds staging (m97 layout).
// Output modes: Cf fp32 row-major | Cb bf16 row-major | Ct bf16 transposed [col][row] packed x4.
__global__ __launch_bounds__(256) void k_gemm(const u16* __restrict__ A, const u16* __restrict__ Bt,
                                              const float* __restrict__ bias,
                                              float* __restrict__ Cf, u16* __restrict__ Cb,
                                              u16* __restrict__ Ct,
                                              int M, int N, int K) {
  __shared__ u16 As[128 * 32];  // unpadded: required by global_load_lds lane mapping
  __shared__ u16 Bs[128 * 32];
  const int tid = threadIdx.x;
  const int wv = tid >> 6, lane = tid & 63;
  const int quad = lane >> 4, l16 = lane & 15;
  const int lr = lane >> 2, lc = (lane & 3) * 8;     // staging: row-in-issue, elem col
  const int m0 = blockIdx.y * 128, n0 = blockIdx.x * 128;
  const int wm = (wv >> 1) * 64, wn = (wv & 1) * 64;
  f32x4 acc[4][4];
  #pragma unroll
  for (int a = 0; a < 4; ++a)
    #pragma unroll
    for (int b = 0; b < 4; ++b) acc[a][b] = (f32x4){0.f, 0.f, 0.f, 0.f};

  for (int kk = 0; kk < K; kk += 32) {
    #pragma unroll
    for (int j = 0; j < 2; ++j) {                    // A: 8 issues of 16 rows
      int e = wv * 2 + j;
      int row = e * 16 + lr;
      gload_lds16(A + (size_t)(m0 + row) * K + kk + lc, As + e * 512);
    }
    #pragma unroll
    for (int j = 0; j < 2; ++j) {                    // B: 8 issues of 16 rows
      int e = wv * 2 + j;
      int row = e * 16 + lr;
      gload_lds16(Bt + (size_t)(n0 + row) * K + kk + lc, Bs + e * 512);
    }
    __syncthreads();
    bf16x8 af[4], bfr[4];
    #pragma unroll
    for (int t = 0; t < 4; ++t) af[t]  = *(const bf16x8*)&As[(wm + t * 16 + l16) * 32 + quad * 8];
    #pragma unroll
    for (int t = 0; t < 4; ++t) bfr[t] = *(const bf16x8*)&Bs[(wn + t * 16 + l16) * 32 + quad * 8];
    #pragma unroll
    for (int mt = 0; mt < 4; ++mt)
      #pragma unroll
      for (int nt = 0; nt < 4; ++nt)
        acc[mt][nt] = __builtin_amdgcn_mfma_f32_16x16x32_bf16(af[mt], bfr[nt], acc[mt][nt], 0, 0, 0);
    __syncthreads();
  }
  #pragma unroll
  for (int mt = 0; mt < 4; ++mt) {
    #pragma unroll
    for (int nt = 0; nt < 4; ++nt) {
      int row = m0 + wm + mt * 16 + quad * 4;   // D: row=(lane>>4)*4+reg, col=lane&15
      int col = n0 + wn + nt * 16 + l16;
      float bv = bias[col];
      if (Ct) {                                  // transposed: Ct[col*M + row..row+3]
        ushort4 o;
        o.x = f2b(acc[mt][nt][0] + bv); o.y = f2b(acc[mt][nt][1] + bv);
        o.z = f2b(acc[mt][nt][2] + bv); o.w = f2b(acc[mt][nt][3] + bv);
        *(ushort4*)&Ct[(size_t)col * M + row] = o;
      } else {
        #pragma unroll
        for (int r = 0; r < 4; ++r) {
          float v = acc[mt][nt][r] + bv;
          if (Cf) Cf[(size_t)(row + r) * N + col] = v;
          else    Cb[(size_t)(row + r) * N + col] = f2b(v);
        }
      }
    }
  }
}

// ---------------- windowed attention ----------------
// grid (4 q-subtiles, 31 windows, 4 batches); block 256 = 4 waves; LDS 54 KB -> 3 blocks/CU.
// Phase 1: S = Q*K^T/8, wave wv owns 16 query rows, in-register softmax over 256 keys.
// Phase 2: O = P*V via Vt ([d][tok] bf16), fully vectorized b128 frag reads.
// Output: plain bf16 stores to parity buffer (w&1) — even windows tile [0,4096),
// odd windows tile [128,3968); no races, no atomics.
#define PSTR 264
__global__ __launch_bounds__(256) void k_attn(const u16* __restrict__ Qb, const u16* __restrict__ Kb,
                                              const u16* __restrict__ Vt,
                                              u16* __restrict__ oA, u16* __restrict__ oB) {
  __shared__ u16 stage[10240];       // Qs(64x32=4KB) + Ks(256x32=16KB); reused as Vs(256x32=16KB)
  __shared__ u16 Pbuf[64 * PSTR];
  u16* Qs = stage;
  u16* Ks = stage + 2048;
  u16* Vs = stage;

  const int tid = threadIdx.x;
  const int wv = tid >> 6, lane = tid & 63;
  const int quad = lane >> 4, l16 = lane & 15;
  const int lr = lane >> 2, lc = (lane & 3) * 8;
  const int qt = blockIdx.x, w = blockIdx.y, b = blockIdx.z;
  const int s0 = w * 128;
  const size_t base = (size_t)b * SEQ * DM;
  const size_t btok = (size_t)b * SEQ;
  const int qrow0 = s0 + qt * 64;

  f32x4 acc[16];
  #pragma unroll
  for (int i = 0; i < 16; ++i) acc[i] = (f32x4){0.f, 0.f, 0.f, 0.f};

  // ---- phase 1: scores ----
  for (int kk = 0; kk < DM; kk += 32) {
    #pragma unroll
    for (int j = 0; j < 5; ++j) {    // 20 issues: 4 Q + 16 K
      int e = wv * 5 + j;
      if (e < 4) {
        int row = e * 16 + lr;
        gload_lds16(Qb + base + (size_t)(qrow0 + row) * DM + kk + lc, Qs + e * 512);
      } else {
        int f = e - 4;
        int row = f * 16 + lr;
        gload_lds16(Kb + base + (size_t)(s0 + row) * DM + kk + lc, Ks + f * 512);
      }
    }
    __syncthreads();
    bf16x8 aq = *(const bf16x8*)&Qs[(wv * 16 + l16) * 32 + quad * 8];
    #pragma unroll
    for (int nt = 0; nt < 16; ++nt) {
      bf16x8 bk = *(const bf16x8*)&Ks[(nt * 16 + l16) * 32 + quad * 8];
      acc[nt] = __builtin_amdgcn_mfma_f32_16x16x32_bf16(aq, bk, acc[nt], 0, 0, 0);
    }
    __syncthreads();
  }

  // ---- softmax (row quad*4+r of this wave's 16 rows; reduce across 16 lanes) ----
  float mx[4] = {-1e30f, -1e30f, -1e30f, -1e30f};
  float sm[4] = {0.f, 0.f, 0.f, 0.f};
  #pragma unroll
  for (int nt = 0; nt < 16; ++nt)
    #pragma unroll
    for (int r = 0; r < 4; ++r) {
      float s = acc[nt][r] * 0.125f;
      acc[nt][r] = s;
      mx[r] = fmaxf(mx[r], s);
    }
  #pragma unroll
  for (int r = 0; r < 4; ++r)
    #pragma unroll
    for (int off = 8; off > 0; off >>= 1)
      mx[r] = fmaxf(mx[r], __shfl_xor(mx[r], off, 64));
  #pragma unroll
  for (int nt = 0; nt < 16; ++nt)
    #pragma unroll
    for (int r = 0; r < 4; ++r) {
      float e = __expf(acc[nt][r] - mx[r]);
      acc[nt][r] = e;
      sm[r] += e;
    }
  #pragma unroll
  for (int r = 0; r < 4; ++r)
    #pragma unroll
    for (int off = 8; off > 0; off >>= 1)
      sm[r] += __shfl_xor(sm[r], off, 64);
  float inv[4];
  #pragma unroll
  for (int r = 0; r < 4; ++r) inv[r] = 1.f / sm[r];
  #pragma unroll
  for (int nt = 0; nt < 16; ++nt)
    #pragma unroll
    for (int r = 0; r < 4; ++r)
      Pbuf[(wv * 16 + quad * 4 + r) * PSTR + nt * 16 + l16] = f2b(acc[nt][r] * inv[r]);
  __syncthreads();

  // ---- phase 2: O = P * V  (M=64, K=256, N=1024 in 4 slabs of 256) ----
  u16* op = ((w & 1) ? oB : oA) + base;
  for (int slab = 0; slab < 4; ++slab) {
    const int nb = slab * 256;
    f32x4 acc2[4][4];
    #pragma unroll
    for (int a = 0; a < 4; ++a)
      #pragma unroll
      for (int c = 0; c < 4; ++c) acc2[a][c] = (f32x4){0.f, 0.f, 0.f, 0.f};
    for (int ks = 0; ks < 8; ++ks) {
      #pragma unroll
      for (int j = 0; j < 4; ++j) {          // 16 issues: Vt rows = d-local 0..255, 32 s each
        int e = wv * 4 + j;
        int row = e * 16 + lr;
        gload_lds16(Vt + (size_t)(nb + row) * NTOK + btok + s0 + ks * 32 + lc, Vs + e * 512);
      }
      __syncthreads();
      bf16x8 af[4];
      #pragma unroll
      for (int mt = 0; mt < 4; ++mt)
        af[mt] = *(const bf16x8*)&Pbuf[(mt * 16 + l16) * PSTR + ks * 32 + quad * 8];
      #pragma unroll
      for (int u = 0; u < 4; ++u) {
        bf16x8 bb = *(const bf16x8*)&Vs[((wv * 4 + u) * 16 + l16) * 32 + quad * 8];
        #pragma unroll
        for (int mt = 0; mt < 4; ++mt)
          acc2[mt][u] = __builtin_amdgcn_mfma_f32_16x16x32_bf16(af[mt], bb, acc2[mt][u], 0, 0, 0);
      }
      __syncthreads();
    }
    #pragma unroll
    for (int mt = 0; mt < 4; ++mt)
      #pragma unroll
      for (int u = 0; u < 4; ++u) {
        int row = qrow0 + mt * 16 + quad * 4;
        int col = nb + (wv * 4 + u) * 16 + l16;
        #pragma unroll
        for (int r = 0; r < 4; ++r)
          op[(size_t)(row + r) * DM + col] = f2b(acc2[mt][u][r]);
      }
  }
}

// ---------------- merge parity buffers -> bf16 (x8 vectorized) ----------------
__global__ __launch_bounds__(256) void k_norm(const u16* __restrict__ oA, const u16* __restrict__ oB,
                                              u16* __restrict__ out, int n8) {
  int i = blockIdx.x * 256 + threadIdx.x;
  if (i >= n8) return;
  int s = (i >> 7) & (SEQ - 1);     // 128 groups of 8 per token row
  uint4 a = ((const uint4*)oA)[i];
  uint4 r = a;
  if (s >= 128 && s < 3968) {       // interior: covered by one even + one odd window
    uint4 bq = ((const uint4*)oB)[i];
    const unsigned* ap = (const unsigned*)&a;
    const unsigned* bp = (const unsigned*)&bq;
    unsigned* rp = (unsigned*)&r;
    #pragma unroll
    for (int k = 0; k < 4; ++k) {
      float lo = 0.5f * (b2f((u16)(ap[k] & 0xffff)) + b2f((u16)(bp[k] & 0xffff)));
      float hi = 0.5f * (b2f((u16)(ap[k] >> 16))    + b2f((u16)(bp[k] >> 16)));
      rp[k] = (unsigned)f2b(lo) | ((unsigned)f2b(hi) << 16);
    }
  }
  ((uint4*)out)[i] = r;
}

extern "C" void kernel_launch(void* const* d_in, const int* in_sizes, int n_in,
                              void* d_out, int out_size, void* d_ws, size_t ws_size,
                              hipStream_t stream) {
  const float* x  = (const float*)d_in[0];
  const float* Wq = (const float*)d_in[1];
  const float* bq = (const float*)d_in[2];
  const float* Wk = (const float*)d_in[3];
  const float* bk = (const float*)d_in[4];
  const float* Wv = (const float*)d_in[5];
  const float* bv = (const float*)d_in[6];
  const float* Wo = (const float*)d_in[7];
  const float* bo = (const float*)d_in[8];
  float* out = (float*)d_out;

  char* ws = (char*)d_ws;
  const size_t XB = (size_t)NTOK * DM * 2;    // 32 MB per bf16 activation buffer
  u16* xb  = (u16*)(ws);                      // x bf16; later the merged attn output
  u16* qb  = (u16*)(ws + XB);
  u16* kb  = (u16*)(ws + 2 * XB);
  u16* vtb = (u16*)(ws + 3 * XB);             // V transposed [d][tok]
  u16* wqt = (u16*)(ws + 4 * XB);
  u16* wkt = wqt + (size_t)DM * DM;
  u16* wvt = wkt + (size_t)DM * DM;
  u16* wot = wvt + (size_t)DM * DM;
  u16* oA  = (u16*)(ws + 4 * XB + 4 * (size_t)DM * DM * 2);
  u16* oB  = oA + (size_t)NTOK * DM;
  // total: 4*32MB + 8MB + 2*32MB = 200 MB

  int n4tok = (int)((size_t)NTOK * DM / 4);
  k_convert<<<(n4tok + 255) / 256, 256, 0, stream>>>(x, xb, n4tok);
  dim3 tpb(32, 8);
  dim3 tgr(DM / 32, DM / 32);
  k_transpose<<<tgr, tpb, 0, stream>>>(Wq, wqt);
  k_transpose<<<tgr, tpb, 0, stream>>>(Wk, wkt);
  k_transpose<<<tgr, tpb, 0, stream>>>(Wv, wvt);
  k_transpose<<<tgr, tpb, 0, stream>>>(Wo, wot);

  dim3 ggr(DM / 128, NTOK / 128);  // (8,128)
  k_gemm<<<ggr, 256, 0, stream>>>(xb, wqt, bq, nullptr, qb, nullptr, NTOK, DM, DM);
  k_gemm<<<ggr, 256, 0, stream>>>(xb, wkt, bk, nullptr, kb, nullptr, NTOK, DM, DM);
  k_gemm<<<ggr, 256, 0, stream>>>(xb, wvt, bv, nullptr, nullptr, vtb, NTOK, DM, DM);

  k_attn<<<dim3(4, NWIN, NBATCH), 256, 0, stream>>>(qb, kb, vtb, oA, oB);

  int n8tok = (int)((size_t)NTOK * DM / 8);
  k_norm<<<(n8tok + 255) / 256, 256, 0, stream>>>(oA, oB, xb, n8tok);
  k_gemm<<<ggr, 256, 0, stream>>>(xb, wot, bo, out, nullptr, nullptr, NTOK, DM, DM);
}

// Round 3
// 483.995 us; speedup vs baseline: 1.2659x; 1.0791x over previous
//
#include <hip/hip_runtime.h>
#include <hip/hip_bf16.h>

typedef unsigned short u16;
typedef short bf16x8 __attribute__((ext_vector_type(8)));
typedef float f32x4 __attribute__((ext_vector_type(4)));

#define DM     1024
#define SEQ    4096
#define NBATCH 4
#define NWIN   31
#define NTOK   16384   // NBATCH*SEQ

__device__ __forceinline__ u16 f2b(float f) {
  union { float f; unsigned u; } x; x.f = f;
  unsigned r = (x.u + 0x7fffu + ((x.u >> 16) & 1u)) >> 16;  // RNE
  return (u16)r;
}
__device__ __forceinline__ float b2f(u16 v) {
  union { unsigned u; float f; } x; x.u = ((unsigned)v) << 16; return x.f;
}
// async global->LDS, 16B per lane. lds dest must be wave-uniform base (+lane*16).
__device__ __forceinline__ void gload_lds16(const u16* g, u16* l) {
  __builtin_amdgcn_global_load_lds(
      (const __attribute__((address_space(1))) void*)g,
      (__attribute__((address_space(3))) void*)l, 16, 0, 0);
}

// ---------------- fp32 -> bf16 convert (x4 vectorized) ----------------
__global__ __launch_bounds__(256) void k_convert(const float* __restrict__ in,
                                                 u16* __restrict__ out, int n4) {
  int i = blockIdx.x * 256 + threadIdx.x;
  if (i >= n4) return;
  float4 v = ((const float4*)in)[i];
  ushort4 o; o.x = f2b(v.x); o.y = f2b(v.y); o.z = f2b(v.z); o.w = f2b(v.w);
  ((ushort4*)out)[i] = o;
}

// ---------------- W (K x N fp32) -> Wt (N x K bf16) ----------------
__global__ __launch_bounds__(256) void k_transpose(const float* __restrict__ W,
                                                   u16* __restrict__ Wt) {
  __shared__ float tile[32][33];
  int n0 = blockIdx.x * 32, k0 = blockIdx.y * 32;
  int tx = threadIdx.x, ty = threadIdx.y;
  #pragma unroll
  for (int i = ty; i < 32; i += 8) tile[i][tx] = W[(size_t)(k0 + i) * DM + n0 + tx];
  __syncthreads();
  #pragma unroll
  for (int i = ty; i < 32; i += 8) Wt[(size_t)(n0 + i) * DM + k0 + tx] = f2b(tile[tx][i]);
}

// ---------------- concat bias [bq|bk|bv] -> 3072 ----------------
__global__ __launch_bounds__(256) void k_catbias(const float* __restrict__ bq,
                                                 const float* __restrict__ bk,
                                                 const float* __restrict__ bv,
                                                 float* __restrict__ o) {
  int i = blockIdx.x * 256 + threadIdx.x;
  if (i >= 3 * DM) return;
  float v = (i < DM) ? bq[i] : (i < 2 * DM) ? bk[i - DM] : bv[i - 2 * DM];
  o[i] = v;
}

// ---------------- bf16 MFMA GEMM: C[M,N] = A[M,K] * Bt[N,K]^T + bias ----------------
// 128x128 tile, 4 waves each 64x64, BK=32, async global_load_lds staging (m97 layout).
// Epilogue: Cf fp32 row-major (ldc=N)  |  col<csplit -> Cb bf16 row-major (ldc)
//           col>=csplit -> Ct bf16 transposed [(col-csplit)][row] packed ushort4.
__global__ __launch_bounds__(256) void k_gemm(const u16* __restrict__ A, const u16* __restrict__ Bt,
                                              const float* __restrict__ bias,
                                              float* __restrict__ Cf,
                                              u16* __restrict__ Cb, int ldc,
                                              u16* __restrict__ Ct, int csplit,
                                              int M, int N, int K) {
  __shared__ u16 As[128 * 32];  // unpadded: required by global_load_lds lane mapping
  __shared__ u16 Bs[128 * 32];
  const int tid = threadIdx.x;
  const int wv = tid >> 6, lane = tid & 63;
  const int quad = lane >> 4, l16 = lane & 15;
  const int lr = lane >> 2, lc = (lane & 3) * 8;
  const int m0 = blockIdx.y * 128, n0 = blockIdx.x * 128;
  const int wm = (wv >> 1) * 64, wn = (wv & 1) * 64;
  f32x4 acc[4][4];
  #pragma unroll
  for (int a = 0; a < 4; ++a)
    #pragma unroll
    for (int b = 0; b < 4; ++b) acc[a][b] = (f32x4){0.f, 0.f, 0.f, 0.f};

  for (int kk = 0; kk < K; kk += 32) {
    #pragma unroll
    for (int j = 0; j < 2; ++j) {                    // A: 8 issues of 16 rows
      int e = wv * 2 + j;
      gload_lds16(A + (size_t)(m0 + e * 16 + lr) * K + kk + lc, As + e * 512);
    }
    #pragma unroll
    for (int j = 0; j < 2; ++j) {                    // B: 8 issues of 16 rows
      int e = wv * 2 + j;
      gload_lds16(Bt + (size_t)(n0 + e * 16 + lr) * K + kk + lc, Bs + e * 512);
    }
    __syncthreads();
    bf16x8 af[4], bfr[4];
    #pragma unroll
    for (int t = 0; t < 4; ++t) af[t]  = *(const bf16x8*)&As[(wm + t * 16 + l16) * 32 + quad * 8];
    #pragma unroll
    for (int t = 0; t < 4; ++t) bfr[t] = *(const bf16x8*)&Bs[(wn + t * 16 + l16) * 32 + quad * 8];
    #pragma unroll
    for (int mt = 0; mt < 4; ++mt)
      #pragma unroll
      for (int nt = 0; nt < 4; ++nt)
        acc[mt][nt] = __builtin_amdgcn_mfma_f32_16x16x32_bf16(af[mt], bfr[nt], acc[mt][nt], 0, 0, 0);
    __syncthreads();
  }
  #pragma unroll
  for (int mt = 0; mt < 4; ++mt) {
    #pragma unroll
    for (int nt = 0; nt < 4; ++nt) {
      int row = m0 + wm + mt * 16 + quad * 4;   // D: row=(lane>>4)*4+reg, col=lane&15
      int col = n0 + wn + nt * 16 + l16;
      float bv = bias[col];
      if (Cf) {
        #pragma unroll
        for (int r = 0; r < 4; ++r)
          Cf[(size_t)(row + r) * N + col] = acc[mt][nt][r] + bv;
      } else if (col < csplit) {
        #pragma unroll
        for (int r = 0; r < 4; ++r)
          Cb[(size_t)(row + r) * ldc + col] = f2b(acc[mt][nt][r] + bv);
      } else {
        ushort4 o;
        o.x = f2b(acc[mt][nt][0] + bv); o.y = f2b(acc[mt][nt][1] + bv);
        o.z = f2b(acc[mt][nt][2] + bv); o.w = f2b(acc[mt][nt][3] + bv);
        *(ushort4*)&Ct[(size_t)(col - csplit) * M + row] = o;
      }
    }
  }
}

// ---------------- windowed attention ----------------
// grid (8 = qt*2+h, 31 windows, 4 batches); block 256 = 4 waves; LDS 54 KB -> 3 blocks/CU.
// Phase 1: S = Q*K^T/8 for 64 query rows (each wave owns 16), in-register softmax over 256 keys.
//          (recomputed by both h-siblings; MFMA is not the binding resource)
// Phase 2: O = P*V for this block's half of the 1024 output dims, via Vt [d][tok].
// Output: plain bf16 stores to parity buffer (w&1): even windows tile [0,4096),
// odd windows tile [128,3968) -> race-free, no atomics.
#define PSTR 264
#define LDQ  2048
__global__ __launch_bounds__(256) void k_attn(const u16* __restrict__ QKb, const u16* __restrict__ Vt,
                                              u16* __restrict__ oA, u16* __restrict__ oB) {
  __shared__ u16 stage[10240];       // Qs(64x32=4KB) + Ks(256x32=16KB); reused as Vs(256x32=16KB)
  __shared__ u16 Pbuf[64 * PSTR];
  u16* Qs = stage;
  u16* Ks = stage + 2048;
  u16* Vs = stage;

  const int tid = threadIdx.x;
  const int wv = tid >> 6, lane = tid & 63;
  const int quad = lane >> 4, l16 = lane & 15;
  const int lr = lane >> 2, lc = (lane & 3) * 8;
  const int qt = blockIdx.x >> 1, h = blockIdx.x & 1;
  const int w = blockIdx.y, b = blockIdx.z;
  const int s0 = w * 128;
  const size_t base2 = (size_t)b * SEQ * LDQ;   // qk buffer base
  const size_t base  = (size_t)b * SEQ * DM;    // output base
  const size_t btok  = (size_t)b * SEQ;
  const int qrow0 = s0 + qt * 64;

  f32x4 acc[16];
  #pragma unroll
  for (int i = 0; i < 16; ++i) acc[i] = (f32x4){0.f, 0.f, 0.f, 0.f};

  // ---- phase 1: scores ----
  for (int kk = 0; kk < DM; kk += 32) {
    #pragma unroll
    for (int j = 0; j < 5; ++j) {    // 20 issues: 4 Q + 16 K
      int e = wv * 5 + j;
      if (e < 4) {
        gload_lds16(QKb + base2 + (size_t)(qrow0 + e * 16 + lr) * LDQ + kk + lc, Qs + e * 512);
      } else {
        int f = e - 4;
        gload_lds16(QKb + DM + base2 + (size_t)(s0 + f * 16 + lr) * LDQ + kk + lc, Ks + f * 512);
      }
    }
    __syncthreads();
    bf16x8 aq = *(const bf16x8*)&Qs[(wv * 16 + l16) * 32 + quad * 8];
    #pragma unroll
    for (int nt = 0; nt < 16; ++nt) {
      bf16x8 bk = *(const bf16x8*)&Ks[(nt * 16 + l16) * 32 + quad * 8];
      acc[nt] = __builtin_amdgcn_mfma_f32_16x16x32_bf16(aq, bk, acc[nt], 0, 0, 0);
    }
    __syncthreads();
  }

  // ---- softmax (row quad*4+r of this wave's 16 rows; reduce across 16 lanes) ----
  float mx[4] = {-1e30f, -1e30f, -1e30f, -1e30f};
  float sm[4] = {0.f, 0.f, 0.f, 0.f};
  #pragma unroll
  for (int nt = 0; nt < 16; ++nt)
    #pragma unroll
    for (int r = 0; r < 4; ++r) {
      float s = acc[nt][r] * 0.125f;
      acc[nt][r] = s;
      mx[r] = fmaxf(mx[r], s);
    }
  #pragma unroll
  for (int r = 0; r < 4; ++r)
    #pragma unroll
    for (int off = 8; off > 0; off >>= 1)
      mx[r] = fmaxf(mx[r], __shfl_xor(mx[r], off, 64));
  #pragma unroll
  for (int nt = 0; nt < 16; ++nt)
    #pragma unroll
    for (int r = 0; r < 4; ++r) {
      float e = __expf(acc[nt][r] - mx[r]);
      acc[nt][r] = e;
      sm[r] += e;
    }
  #pragma unroll
  for (int r = 0; r < 4; ++r)
    #pragma unroll
    for (int off = 8; off > 0; off >>= 1)
      sm[r] += __shfl_xor(sm[r], off, 64);
  float inv[4];
  #pragma unroll
  for (int r = 0; r < 4; ++r) inv[r] = 1.f / sm[r];
  #pragma unroll
  for (int nt = 0; nt < 16; ++nt)
    #pragma unroll
    for (int r = 0; r < 4; ++r)
      Pbuf[(wv * 16 + quad * 4 + r) * PSTR + nt * 16 + l16] = f2b(acc[nt][r] * inv[r]);
  __syncthreads();

  // ---- phase 2: O = P * V  (M=64, K=256, this block's N-half = 2 slabs of 256) ----
  u16* op = ((w & 1) ? oB : oA) + base;
  for (int sl = 0; sl < 2; ++sl) {
    const int nb = (h * 2 + sl) * 256;
    f32x4 acc2[4][4];
    #pragma unroll
    for (int a = 0; a < 4; ++a)
      #pragma unroll
      for (int c = 0; c < 4; ++c) acc2[a][c] = (f32x4){0.f, 0.f, 0.f, 0.f};
    for (int ks = 0; ks < 8; ++ks) {
      #pragma unroll
      for (int j = 0; j < 4; ++j) {          // 16 issues: 256 d-rows x 32 tokens
        int e = wv * 4 + j;
        gload_lds16(Vt + (size_t)(nb + e * 16 + lr) * NTOK + btok + s0 + ks * 32 + lc, Vs + e * 512);
      }
      __syncthreads();
      bf16x8 af[4];
      #pragma unroll
      for (int mt = 0; mt < 4; ++mt)
        af[mt] = *(const bf16x8*)&Pbuf[(mt * 16 + l16) * PSTR + ks * 32 + quad * 8];
      #pragma unroll
      for (int u = 0; u < 4; ++u) {
        bf16x8 bb = *(const bf16x8*)&Vs[((wv * 4 + u) * 16 + l16) * 32 + quad * 8];
        #pragma unroll
        for (int mt = 0; mt < 4; ++mt)
          acc2[mt][u] = __builtin_amdgcn_mfma_f32_16x16x32_bf16(af[mt], bb, acc2[mt][u], 0, 0, 0);
      }
      __syncthreads();
    }
    #pragma unroll
    for (int mt = 0; mt < 4; ++mt)
      #pragma unroll
      for (int u = 0; u < 4; ++u) {
        int row = qrow0 + mt * 16 + quad * 4;
        int col = nb + (wv * 4 + u) * 16 + l16;
        #pragma unroll
        for (int r = 0; r < 4; ++r)
          op[(size_t)(row + r) * DM + col] = f2b(acc2[mt][u][r]);
      }
  }
}

// ---------------- merge parity buffers -> bf16 (x8 vectorized) ----------------
__global__ __launch_bounds__(256) void k_norm(const u16* __restrict__ oA, const u16* __restrict__ oB,
                                              u16* __restrict__ out, int n8) {
  int i = blockIdx.x * 256 + threadIdx.x;
  if (i >= n8) return;
  int s = (i >> 7) & (SEQ - 1);     // 128 groups of 8 per token row
  uint4 a = ((const uint4*)oA)[i];
  uint4 r = a;
  if (s >= 128 && s < 3968) {       // interior: one even + one odd window
    uint4 bq = ((const uint4*)oB)[i];
    const unsigned* ap = (const unsigned*)&a;
    const unsigned* bp = (const unsigned*)&bq;
    unsigned* rp = (unsigned*)&r;
    #pragma unroll
    for (int k = 0; k < 4; ++k) {
      float lo = 0.5f * (b2f((u16)(ap[k] & 0xffff)) + b2f((u16)(bp[k] & 0xffff)));
      float hi = 0.5f * (b2f((u16)(ap[k] >> 16))    + b2f((u16)(bp[k] >> 16)));
      rp[k] = (unsigned)f2b(lo) | ((unsigned)f2b(hi) << 16);
    }
  }
  ((uint4*)out)[i] = r;
}

extern "C" void kernel_launch(void* const* d_in, const int* in_sizes, int n_in,
                              void* d_out, int out_size, void* d_ws, size_t ws_size,
                              hipStream_t stream) {
  const float* x  = (const float*)d_in[0];
  const float* Wq = (const float*)d_in[1];
  const float* bq = (const float*)d_in[2];
  const float* Wk = (const float*)d_in[3];
  const float* bk = (const float*)d_in[4];
  const float* Wv = (const float*)d_in[5];
  const float* bv = (const float*)d_in[6];
  const float* Wo = (const float*)d_in[7];
  const float* bo = (const float*)d_in[8];
  float* out = (float*)d_out;

  char* ws = (char*)d_ws;
  const size_t MB = 1024 * 1024;
  u16*   xb   = (u16*)(ws);                 // 32 MB: x bf16; later merged attn output
  u16*   qkb  = (u16*)(ws + 32 * MB);       // 64 MB: [tok][2048] q|k
  u16*   vtb  = (u16*)(ws + 96 * MB);       // 32 MB: V transposed [d][tok]
  u16*   wqt  = (u16*)(ws + 128 * MB);      // 8 MB: wqt|wkt|wvt|wot contiguous
  u16*   wkt  = wqt + (size_t)DM * DM;
  u16*   wvt  = wkt + (size_t)DM * DM;
  u16*   wot  = wvt + (size_t)DM * DM;
  float* bcat = (float*)(ws + 136 * MB);    // 12 KB
  u16*   oA   = (u16*)(ws + 137 * MB);      // 32 MB
  u16*   oB   = (u16*)(ws + 169 * MB);      // 32 MB  (end: 201 MB)

  int n4tok = (int)((size_t)NTOK * DM / 4);
  k_convert<<<(n4tok + 255) / 256, 256, 0, stream>>>(x, xb, n4tok);
  dim3 tpb(32, 8);
  dim3 tgr(DM / 32, DM / 32);
  k_transpose<<<tgr, tpb, 0, stream>>>(Wq, wqt);
  k_transpose<<<tgr, tpb, 0, stream>>>(Wk, wkt);
  k_transpose<<<tgr, tpb, 0, stream>>>(Wv, wvt);
  k_transpose<<<tgr, tpb, 0, stream>>>(Wo, wot);
  k_catbias<<<12, 256, 0, stream>>>(bq, bk, bv, bcat);

  // fused QKV GEMM: N=3072 over [wqt|wkt|wvt]; q,k -> qkb row-major; v -> vtb transposed
  k_gemm<<<dim3(3 * DM / 128, NTOK / 128), 256, 0, stream>>>(
      xb, wqt, bcat, nullptr, qkb, 2048, vtb, 2048, NTOK, 3 * DM, DM);

  k_attn<<<dim3(8, NWIN, NBATCH), 256, 0, stream>>>(qkb, vtb, oA, oB);

  int n8tok = (int)((size_t)NTOK * DM / 8);
  k_norm<<<(n8tok + 255) / 256, 256, 0, stream>>>(oA, oB, xb, n8tok);

  k_gemm<<<dim3(DM / 128, NTOK / 128), 256, 0, stream>>>(
      xb, wot, bo, out, nullptr, DM, nullptr, DM, NTOK, DM, DM);
}

// Round 4
// 441.440 us; speedup vs baseline: 1.3879x; 1.0964x over previous
//
#include <hip/hip_runtime.h>
#include <hip/hip_bf16.h>

typedef unsigned short u16;
typedef short bf16x8 __attribute__((ext_vector_type(8)));
typedef float f32x4 __attribute__((ext_vector_type(4)));

#define DM     1024
#define SEQ    4096
#define NBATCH 4
#define NWIN   31
#define NTOK   16384   // NBATCH*SEQ

__device__ __forceinline__ u16 f2b(float f) {
  union { float f; unsigned u; } x; x.f = f;
  unsigned r = (x.u + 0x7fffu + ((x.u >> 16) & 1u)) >> 16;  // RNE
  return (u16)r;
}
__device__ __forceinline__ float b2f(u16 v) {
  union { unsigned u; float f; } x; x.u = ((unsigned)v) << 16; return x.f;
}
// async global->LDS, 16B per lane. lds dest is wave-uniform base + lane*16.
__device__ __forceinline__ void gload_lds16(const u16* g, u16* l) {
  __builtin_amdgcn_global_load_lds(
      (const __attribute__((address_space(1))) void*)g,
      (__attribute__((address_space(3))) void*)l, 16, 0, 0);
}

// ---------------- fp32 -> bf16 convert (x4 vectorized) ----------------
__global__ __launch_bounds__(256) void k_convert(const float* __restrict__ in,
                                                 u16* __restrict__ out, int n4) {
  int i = blockIdx.x * 256 + threadIdx.x;
  if (i >= n4) return;
  float4 v = ((const float4*)in)[i];
  ushort4 o; o.x = f2b(v.x); o.y = f2b(v.y); o.z = f2b(v.z); o.w = f2b(v.w);
  ((ushort4*)out)[i] = o;
}

// ---------------- 4x W (K x N fp32) -> Wt (N x K bf16), fused ----------------
__global__ __launch_bounds__(256) void k_transpose4(const float* __restrict__ W0,
                                                    const float* __restrict__ W1,
                                                    const float* __restrict__ W2,
                                                    const float* __restrict__ W3,
                                                    u16* __restrict__ Wt) {
  __shared__ float tile[32][33];
  int z = blockIdx.z;
  const float* W = (z == 0) ? W0 : (z == 1) ? W1 : (z == 2) ? W2 : W3;
  u16* dst = Wt + (size_t)z * DM * DM;
  int n0 = blockIdx.x * 32, k0 = blockIdx.y * 32;
  int tx = threadIdx.x, ty = threadIdx.y;
  #pragma unroll
  for (int i = ty; i < 32; i += 8) tile[i][tx] = W[(size_t)(k0 + i) * DM + n0 + tx];
  __syncthreads();
  #pragma unroll
  for (int i = ty; i < 32; i += 8) dst[(size_t)(n0 + i) * DM + k0 + tx] = f2b(tile[tx][i]);
}

// ---------------- concat bias [bq|bk|bv] -> 3072 ----------------
__global__ __launch_bounds__(256) void k_catbias(const float* __restrict__ bq,
                                                 const float* __restrict__ bk,
                                                 const float* __restrict__ bv,
                                                 float* __restrict__ o) {
  int i = blockIdx.x * 256 + threadIdx.x;
  if (i >= 3 * DM) return;
  float v = (i < DM) ? bq[i] : (i < 2 * DM) ? bk[i - DM] : bv[i - 2 * DM];
  o[i] = v;
}

// ---------------- bf16 MFMA GEMM: C[M,N] = A[M,K] * Bt[N,K]^T + bias ----------------
// 128x128 tile, 4 waves each 64x64, BK=64, async global_load_lds staging with
// XOR chunk swizzle (physical chunk = logical ^ (row&7)) -> conflict-free b128 frag reads.
// Epilogue: Cf fp32 row-major (ldc=N)  |  col<csplit -> Cb bf16 row-major (ldc)
//           col>=csplit -> Ct bf16 transposed [(col-csplit)][row] packed ushort4.
__global__ __launch_bounds__(256) void k_gemm(const u16* __restrict__ A, const u16* __restrict__ Bt,
                                              const float* __restrict__ bias,
                                              float* __restrict__ Cf,
                                              u16* __restrict__ Cb, int ldc,
                                              u16* __restrict__ Ct, int csplit,
                                              int M, int N, int K) {
  __shared__ u16 As[128 * 64];
  __shared__ u16 Bs[128 * 64];
  const int tid = threadIdx.x;
  const int wv = tid >> 6, lane = tid & 63;
  const int quad = lane >> 4, l16 = lane & 15;
  const int lr8 = lane >> 3;                       // row within an 8-row issue
  const int lc8 = (((lane & 7) ^ (lr8 & 7)) * 8);  // swizzled global chunk for this lane
  const int m0 = blockIdx.y * 128, n0 = blockIdx.x * 128;
  const int wm = (wv >> 1) * 64, wn = (wv & 1) * 64;
  const int k7 = l16 & 7;                          // frag-read swizzle key
  f32x4 acc[4][4];
  #pragma unroll
  for (int a = 0; a < 4; ++a)
    #pragma unroll
    for (int b = 0; b < 4; ++b) acc[a][b] = (f32x4){0.f, 0.f, 0.f, 0.f};

  for (int kk = 0; kk < K; kk += 64) {
    #pragma unroll
    for (int j = 0; j < 4; ++j) {                  // A: 16 issues of 8 rows
      int e = wv * 4 + j;
      gload_lds16(A + (size_t)(m0 + e * 8 + lr8) * K + kk + lc8, As + e * 512);
    }
    #pragma unroll
    for (int j = 0; j < 4; ++j) {                  // B: 16 issues of 8 rows
      int e = wv * 4 + j;
      gload_lds16(Bt + (size_t)(n0 + e * 8 + lr8) * K + kk + lc8, Bs + e * 512);
    }
    __syncthreads();
    #pragma unroll
    for (int h = 0; h < 2; ++h) {
      bf16x8 af[4], bfr[4];
      #pragma unroll
      for (int t = 0; t < 4; ++t)
        af[t]  = *(const bf16x8*)&As[(wm + t * 16 + l16) * 64 + ((h * 4 + quad) ^ k7) * 8];
      #pragma unroll
      for (int t = 0; t < 4; ++t)
        bfr[t] = *(const bf16x8*)&Bs[(wn + t * 16 + l16) * 64 + ((h * 4 + quad) ^ k7) * 8];
      #pragma unroll
      for (int mt = 0; mt < 4; ++mt)
        #pragma unroll
        for (int nt = 0; nt < 4; ++nt)
          acc[mt][nt] = __builtin_amdgcn_mfma_f32_16x16x32_bf16(af[mt], bfr[nt], acc[mt][nt], 0, 0, 0);
    }
    __syncthreads();
  }
  #pragma unroll
  for (int mt = 0; mt < 4; ++mt) {
    #pragma unroll
    for (int nt = 0; nt < 4; ++nt) {
      int row = m0 + wm + mt * 16 + quad * 4;   // D: row=(lane>>4)*4+reg, col=lane&15
      int col = n0 + wn + nt * 16 + l16;
      float bv = bias[col];
      if (Cf) {
        #pragma unroll
        for (int r = 0; r < 4; ++r)
          Cf[(size_t)(row + r) * N + col] = acc[mt][nt][r] + bv;
      } else if (col < csplit) {
        #pragma unroll
        for (int r = 0; r < 4; ++r)
          Cb[(size_t)(row + r) * ldc + col] = f2b(acc[mt][nt][r] + bv);
      } else {
        ushort4 o;
        o.x = f2b(acc[mt][nt][0] + bv); o.y = f2b(acc[mt][nt][1] + bv);
        o.z = f2b(acc[mt][nt][2] + bv); o.w = f2b(acc[mt][nt][3] + bv);
        *(ushort4*)&Ct[(size_t)(col - csplit) * M + row] = o;
      }
    }
  }
}

// ---------------- windowed attention ----------------
// grid (8 = qt*2+h, 31 windows, 4 batches); block 256 = 4 waves; LDS 54 KB -> 3 blocks/CU.
// Phase 1: S = Q*K^T/8 for 64 query rows (wave owns 16), in-register softmax over 256 keys.
// Phase 2: O = P*V for this block's half of the 1024 dims, via Vt [d][tok].
// Staging uses XOR chunk swizzle (key (r>>1)&3) -> conflict-free b128 frag reads.
// Output: bf16 stores to parity buffer (w&1): even windows tile [0,4096), odd tile
// [128,3968) -> race-free, no atomics.
#define PSTR 264
#define LDQ  2048
__global__ __launch_bounds__(256) void k_attn(const u16* __restrict__ QKb, const u16* __restrict__ Vt,
                                              u16* __restrict__ oA, u16* __restrict__ oB) {
  __shared__ u16 stage[10240];       // Qs(64x32=4KB) + Ks(256x32=16KB); reused as Vs(256x32=16KB)
  __shared__ u16 Pbuf[64 * PSTR];
  u16* Qs = stage;
  u16* Ks = stage + 2048;
  u16* Vs = stage;

  const int tid = threadIdx.x;
  const int wv = tid >> 6, lane = tid & 63;
  const int quad = lane >> 4, l16 = lane & 15;
  const int lr = lane >> 2;
  const int lc = (((lane & 3) ^ ((lr >> 1) & 3)) * 8);  // swizzled chunk
  const int k3 = (l16 >> 1) & 3;                        // frag-read swizzle key
  const int qt = blockIdx.x >> 1, h = blockIdx.x & 1;
  const int w = blockIdx.y, b = blockIdx.z;
  const int s0 = w * 128;
  const size_t base2 = (size_t)b * SEQ * LDQ;   // qk buffer base
  const size_t base  = (size_t)b * SEQ * DM;    // output base
  const size_t btok  = (size_t)b * SEQ;
  const int qrow0 = s0 + qt * 64;

  f32x4 acc[16];
  #pragma unroll
  for (int i = 0; i < 16; ++i) acc[i] = (f32x4){0.f, 0.f, 0.f, 0.f};

  // ---- phase 1: scores ----
  for (int kk = 0; kk < DM; kk += 32) {
    #pragma unroll
    for (int j = 0; j < 5; ++j) {    // 20 issues: 4 Q + 16 K
      int e = wv * 5 + j;
      if (e < 4) {
        gload_lds16(QKb + base2 + (size_t)(qrow0 + e * 16 + lr) * LDQ + kk + lc, Qs + e * 512);
      } else {
        int f = e - 4;
        gload_lds16(QKb + DM + base2 + (size_t)(s0 + f * 16 + lr) * LDQ + kk + lc, Ks + f * 512);
      }
    }
    __syncthreads();
    bf16x8 aq = *(const bf16x8*)&Qs[(wv * 16 + l16) * 32 + (quad ^ k3) * 8];
    #pragma unroll
    for (int nt = 0; nt < 16; ++nt) {
      bf16x8 bk = *(const bf16x8*)&Ks[(nt * 16 + l16) * 32 + (quad ^ k3) * 8];
      acc[nt] = __builtin_amdgcn_mfma_f32_16x16x32_bf16(aq, bk, acc[nt], 0, 0, 0);
    }
    __syncthreads();
  }

  // ---- softmax (row quad*4+r of this wave's 16 rows; reduce across 16 lanes) ----
  float mx[4] = {-1e30f, -1e30f, -1e30f, -1e30f};
  float sm[4] = {0.f, 0.f, 0.f, 0.f};
  #pragma unroll
  for (int nt = 0; nt < 16; ++nt)
    #pragma unroll
    for (int r = 0; r < 4; ++r) {
      float s = acc[nt][r] * 0.125f;
      acc[nt][r] = s;
      mx[r] = fmaxf(mx[r], s);
    }
  #pragma unroll
  for (int r = 0; r < 4; ++r)
    #pragma unroll
    for (int off = 8; off > 0; off >>= 1)
      mx[r] = fmaxf(mx[r], __shfl_xor(mx[r], off, 64));
  #pragma unroll
  for (int nt = 0; nt < 16; ++nt)
    #pragma unroll
    for (int r = 0; r < 4; ++r) {
      float e = __expf(acc[nt][r] - mx[r]);
      acc[nt][r] = e;
      sm[r] += e;
    }
  #pragma unroll
  for (int r = 0; r < 4; ++r)
    #pragma unroll
    for (int off = 8; off > 0; off >>= 1)
      sm[r] += __shfl_xor(sm[r], off, 64);
  float inv[4];
  #pragma unroll
  for (int r = 0; r < 4; ++r) inv[r] = 1.f / sm[r];
  #pragma unroll
  for (int nt = 0; nt < 16; ++nt)
    #pragma unroll
    for (int r = 0; r < 4; ++r)
      Pbuf[(wv * 16 + quad * 4 + r) * PSTR + nt * 16 + l16] = f2b(acc[nt][r] * inv[r]);
  __syncthreads();

  // ---- phase 2: O = P * V  (M=64, K=256, this block's N-half = 2 slabs of 256) ----
  u16* op = ((w & 1) ? oB : oA) + base;
  for (int sl = 0; sl < 2; ++sl) {
    const int nb = (h * 2 + sl) * 256;
    f32x4 acc2[4][4];
    #pragma unroll
    for (int a = 0; a < 4; ++a)
      #pragma unroll
      for (int c = 0; c < 4; ++c) acc2[a][c] = (f32x4){0.f, 0.f, 0.f, 0.f};
    for (int ks = 0; ks < 8; ++ks) {
      #pragma unroll
      for (int j = 0; j < 4; ++j) {          // 16 issues: 256 d-rows x 32 tokens
        int e = wv * 4 + j;
        gload_lds16(Vt + (size_t)(nb + e * 16 + lr) * NTOK + btok + s0 + ks * 32 + lc, Vs + e * 512);
      }
      __syncthreads();
      bf16x8 af[4];
      #pragma unroll
      for (int mt = 0; mt < 4; ++mt)
        af[mt] = *(const bf16x8*)&Pbuf[(mt * 16 + l16) * PSTR + ks * 32 + quad * 8];
      #pragma unroll
      for (int u = 0; u < 4; ++u) {
        bf16x8 bb = *(const bf16x8*)&Vs[((wv * 4 + u) * 16 + l16) * 32 + (quad ^ k3) * 8];
        #pragma unroll
        for (int mt = 0; mt < 4; ++mt)
          acc2[mt][u] = __builtin_amdgcn_mfma_f32_16x16x32_bf16(af[mt], bb, acc2[mt][u], 0, 0, 0);
      }
      __syncthreads();
    }
    #pragma unroll
    for (int mt = 0; mt < 4; ++mt)
      #pragma unroll
      for (int u = 0; u < 4; ++u) {
        int row = qrow0 + mt * 16 + quad * 4;
        int col = nb + (wv * 4 + u) * 16 + l16;
        #pragma unroll
        for (int r = 0; r < 4; ++r)
          op[(size_t)(row + r) * DM + col] = f2b(acc2[mt][u][r]);
      }
  }
}

// ---------------- merge parity buffers -> bf16 (x8 vectorized) ----------------
__global__ __launch_bounds__(256) void k_norm(const u16* __restrict__ oA, const u16* __restrict__ oB,
                                              u16* __restrict__ out, int n8) {
  int i = blockIdx.x * 256 + threadIdx.x;
  if (i >= n8) return;
  int s = (i >> 7) & (SEQ - 1);     // 128 groups of 8 per token row
  uint4 a = ((const uint4*)oA)[i];
  uint4 r = a;
  if (s >= 128 && s < 3968) {       // interior: one even + one odd window
    uint4 bq = ((const uint4*)oB)[i];
    const unsigned* ap = (const unsigned*)&a;
    const unsigned* bp = (const unsigned*)&bq;
    unsigned* rp = (unsigned*)&r;
    #pragma unroll
    for (int k = 0; k < 4; ++k) {
      float lo = 0.5f * (b2f((u16)(ap[k] & 0xffff)) + b2f((u16)(bp[k] & 0xffff)));
      float hi = 0.5f * (b2f((u16)(ap[k] >> 16))    + b2f((u16)(bp[k] >> 16)));
      rp[k] = (unsigned)f2b(lo) | ((unsigned)f2b(hi) << 16);
    }
  }
  ((uint4*)out)[i] = r;
}

extern "C" void kernel_launch(void* const* d_in, const int* in_sizes, int n_in,
                              void* d_out, int out_size, void* d_ws, size_t ws_size,
                              hipStream_t stream) {
  const float* x  = (const float*)d_in[0];
  const float* Wq = (const float*)d_in[1];
  const float* bq = (const float*)d_in[2];
  const float* Wk = (const float*)d_in[3];
  const float* bk = (const float*)d_in[4];
  const float* Wv = (const float*)d_in[5];
  const float* bv = (const float*)d_in[6];
  const float* Wo = (const float*)d_in[7];
  const float* bo = (const float*)d_in[8];
  float* out = (float*)d_out;

  char* ws = (char*)d_ws;
  const size_t MB = 1024 * 1024;
  u16*   xb   = (u16*)(ws);                 // 32 MB: x bf16; later merged attn output
  u16*   qkb  = (u16*)(ws + 32 * MB);       // 64 MB: [tok][2048] q|k
  u16*   vtb  = (u16*)(ws + 96 * MB);       // 32 MB: V transposed [d][tok]
  u16*   wqt  = (u16*)(ws + 128 * MB);      // 8 MB: wqt|wkt|wvt|wot contiguous
  float* bcat = (float*)(ws + 136 * MB);    // 12 KB
  u16*   oA   = (u16*)(ws + 137 * MB);      // 32 MB
  u16*   oB   = (u16*)(ws + 169 * MB);      // 32 MB  (end: 201 MB)

  int n4tok = (int)((size_t)NTOK * DM / 4);
  k_convert<<<(n4tok + 255) / 256, 256, 0, stream>>>(x, xb, n4tok);
  k_transpose4<<<dim3(DM / 32, DM / 32, 4), dim3(32, 8), 0, stream>>>(Wq, Wk, Wv, Wo, wqt);
  k_catbias<<<12, 256, 0, stream>>>(bq, bk, bv, bcat);

  // fused QKV GEMM: N=3072 over [wqt|wkt|wvt]; q,k -> qkb row-major; v -> vtb transposed
  k_gemm<<<dim3(3 * DM / 128, NTOK / 128), 256, 0, stream>>>(
      xb, wqt, bcat, nullptr, qkb, 2048, vtb, 2048, NTOK, 3 * DM, DM);

  k_attn<<<dim3(8, NWIN, NBATCH), 256, 0, stream>>>(qkb, vtb, oA, oB);

  int n8tok = (int)((size_t)NTOK * DM / 8);
  k_norm<<<(n8tok + 255) / 256, 256, 0, stream>>>(oA, oB, xb, n8tok);

  u16* wot = wqt + 3 * (size_t)DM * DM;
  k_gemm<<<dim3(DM / 128, NTOK / 128), 256, 0, stream>>>(
      xb, wot, bo, out, nullptr, DM, nullptr, DM, NTOK, DM, DM);
}

// Round 5
// 426.965 us; speedup vs baseline: 1.4350x; 1.0339x over previous
//
#include <hip/hip_runtime.h>
#include <hip/hip_bf16.h>

typedef unsigned short u16;
typedef short bf16x8 __attribute__((ext_vector_type(8)));
typedef float f32x4 __attribute__((ext_vector_type(4)));
typedef float f32x16 __attribute__((ext_vector_type(16)));

#define DM     1024
#define SEQ    4096
#define NBATCH 4
#define NWIN   31
#define NTOK   16384   // NBATCH*SEQ

__device__ __forceinline__ u16 f2b(float f) {
  union { float f; unsigned u; } x; x.f = f;
  unsigned r = (x.u + 0x7fffu + ((x.u >> 16) & 1u)) >> 16;  // RNE
  return (u16)r;
}
__device__ __forceinline__ float b2f(u16 v) {
  union { unsigned u; float f; } x; x.u = ((unsigned)v) << 16; return x.f;
}
// async global->LDS, 16B per lane. lds dest is wave-uniform base + lane*16.
__device__ __forceinline__ void gload_lds16(const u16* g, u16* l) {
  __builtin_amdgcn_global_load_lds(
      (const __attribute__((address_space(1))) void*)g,
      (__attribute__((address_space(3))) void*)l, 16, 0, 0);
}

// ---------------- fp32 -> bf16 convert (x4 vectorized) ----------------
__global__ __launch_bounds__(256) void k_convert(const float* __restrict__ in,
                                                 u16* __restrict__ out, int n4) {
  int i = blockIdx.x * 256 + threadIdx.x;
  if (i >= n4) return;
  float4 v = ((const float4*)in)[i];
  ushort4 o; o.x = f2b(v.x); o.y = f2b(v.y); o.z = f2b(v.z); o.w = f2b(v.w);
  ((ushort4*)out)[i] = o;
}

// ---------------- 4x W (K x N fp32) -> Wt (N x K bf16), fused ----------------
__global__ __launch_bounds__(256) void k_transpose4(const float* __restrict__ W0,
                                                    const float* __restrict__ W1,
                                                    const float* __restrict__ W2,
                                                    const float* __restrict__ W3,
                                                    u16* __restrict__ Wt) {
  __shared__ float tile[32][33];
  int z = blockIdx.z;
  const float* W = (z == 0) ? W0 : (z == 1) ? W1 : (z == 2) ? W2 : W3;
  u16* dst = Wt + (size_t)z * DM * DM;
  int n0 = blockIdx.x * 32, k0 = blockIdx.y * 32;
  int tx = threadIdx.x, ty = threadIdx.y;
  #pragma unroll
  for (int i = ty; i < 32; i += 8) tile[i][tx] = W[(size_t)(k0 + i) * DM + n0 + tx];
  __syncthreads();
  #pragma unroll
  for (int i = ty; i < 32; i += 8) dst[(size_t)(n0 + i) * DM + k0 + tx] = f2b(tile[tx][i]);
}

// ---------------- concat bias [bq|bk|bv] -> 3072 ----------------
__global__ __launch_bounds__(256) void k_catbias(const float* __restrict__ bq,
                                                 const float* __restrict__ bk,
                                                 const float* __restrict__ bv,
                                                 float* __restrict__ o) {
  int i = blockIdx.x * 256 + threadIdx.x;
  if (i >= 3 * DM) return;
  float v = (i < DM) ? bq[i] : (i < 2 * DM) ? bk[i - DM] : bv[i - 2 * DM];
  o[i] = v;
}

// ---------------- bf16 MFMA GEMM: C[M,N] = A[M,K] * Bt[N,K]^T + bias ----------------
// 128x128 tile, 4 waves each 64x64 (2x2 of 32x32x16 MFMA), BK=64, async
// global_load_lds staging with XOR chunk swizzle (phys chunk = logical ^ (row&7))
// -> conflict-free b128 frag reads. launch_bounds(256,4): keep addresses resident.
// Epilogue: Cf fp32 row-major | col<csplit -> Cb bf16 row-major (ldc)
//           col>=csplit -> Ct bf16 transposed [(col-csplit)][row] packed ushort4.
__global__ __launch_bounds__(256, 4) void k_gemm(const u16* __restrict__ A, const u16* __restrict__ Bt,
                                                 const float* __restrict__ bias,
                                                 float* __restrict__ Cf,
                                                 u16* __restrict__ Cb, int ldc,
                                                 u16* __restrict__ Ct, int csplit,
                                                 int M, int N, int K) {
  __shared__ u16 As[128 * 64];
  __shared__ u16 Bs[128 * 64];
  const int tid = threadIdx.x;
  const int wv = tid >> 6, lane = tid & 63;
  const int l31 = lane & 31, hl = lane >> 5;       // frag row / k-half
  const int lr8 = lane >> 3;                       // staging: row within 8-row issue
  const int lc8 = (((lane & 7) ^ (lr8 & 7)) * 8);  // staging: swizzled chunk
  const int m0 = blockIdx.y * 128, n0 = blockIdx.x * 128;
  const int wm = (wv >> 1) * 64, wn = (wv & 1) * 64;
  const int k7 = l31 & 7;                          // frag-read swizzle key
  f32x16 acc[2][2];
  #pragma unroll
  for (int a = 0; a < 2; ++a)
    #pragma unroll
    for (int b = 0; b < 2; ++b)
      #pragma unroll
      for (int r = 0; r < 16; ++r) acc[a][b][r] = 0.f;

  for (int kk = 0; kk < K; kk += 64) {
    #pragma unroll
    for (int j = 0; j < 4; ++j) {                  // A: 16 issues of 8 rows
      int e = wv * 4 + j;
      gload_lds16(A + (size_t)(m0 + e * 8 + lr8) * K + kk + lc8, As + e * 512);
    }
    #pragma unroll
    for (int j = 0; j < 4; ++j) {                  // B: 16 issues of 8 rows
      int e = wv * 4 + j;
      gload_lds16(Bt + (size_t)(n0 + e * 8 + lr8) * K + kk + lc8, Bs + e * 512);
    }
    __syncthreads();
    #pragma unroll
    for (int s = 0; s < 4; ++s) {                  // 4 k-steps of 16
      const int ch = ((2 * s + hl) ^ k7) * 8;
      bf16x8 af[2], bfr[2];
      #pragma unroll
      for (int t = 0; t < 2; ++t) af[t]  = *(const bf16x8*)&As[(wm + t * 32 + l31) * 64 + ch];
      #pragma unroll
      for (int t = 0; t < 2; ++t) bfr[t] = *(const bf16x8*)&Bs[(wn + t * 32 + l31) * 64 + ch];
      #pragma unroll
      for (int mt = 0; mt < 2; ++mt)
        #pragma unroll
        for (int nt = 0; nt < 2; ++nt)
          acc[mt][nt] = __builtin_amdgcn_mfma_f32_32x32x16_bf16(af[mt], bfr[nt], acc[mt][nt], 0, 0, 0);
    }
    __syncthreads();
  }
  // D layout (32x32): col = lane&31, row = (reg&3) + 8*(reg>>2) + 4*(lane>>5)
  #pragma unroll
  for (int mt = 0; mt < 2; ++mt) {
    #pragma unroll
    for (int nt = 0; nt < 2; ++nt) {
      int col = n0 + wn + nt * 32 + l31;
      float bv = bias[col];
      #pragma unroll
      for (int g = 0; g < 4; ++g) {
        int row = m0 + wm + mt * 32 + g * 8 + hl * 4;
        if (Cf) {
          #pragma unroll
          for (int r = 0; r < 4; ++r)
            Cf[(size_t)(row + r) * N + col] = acc[mt][nt][g * 4 + r] + bv;
        } else if (col < csplit) {
          #pragma unroll
          for (int r = 0; r < 4; ++r)
            Cb[(size_t)(row + r) * ldc + col] = f2b(acc[mt][nt][g * 4 + r] + bv);
        } else {
          ushort4 o;
          o.x = f2b(acc[mt][nt][g * 4 + 0] + bv); o.y = f2b(acc[mt][nt][g * 4 + 1] + bv);
          o.z = f2b(acc[mt][nt][g * 4 + 2] + bv); o.w = f2b(acc[mt][nt][g * 4 + 3] + bv);
          *(ushort4*)&Ct[(size_t)(col - csplit) * M + row] = o;
        }
      }
    }
  }
}

// ---------------- windowed attention ----------------
// grid (8 = qt*2+h, 31 windows, 4 batches); block 256 = 4 waves; LDS 54 KB -> 3 blocks/CU.
// Phase 1: S = Q*K^T/8 for 64 query rows (wave owns 16), in-register softmax over 256 keys.
// Phase 2: O = P*V for this block's half of the 1024 dims, via Vt [d][tok].
// Staging uses XOR chunk swizzle (key (r>>1)&3) -> conflict-free b128 frag reads.
// Output: bf16 stores to parity buffer (w&1): even windows tile [0,4096), odd tile
// [128,3968) -> race-free, no atomics.
#define PSTR 264
#define LDQ  2048
__global__ __launch_bounds__(256) void k_attn(const u16* __restrict__ QKb, const u16* __restrict__ Vt,
                                              u16* __restrict__ oA, u16* __restrict__ oB) {
  __shared__ u16 stage[10240];       // Qs(64x32=4KB) + Ks(256x32=16KB); reused as Vs(256x32=16KB)
  __shared__ u16 Pbuf[64 * PSTR];
  u16* Qs = stage;
  u16* Ks = stage + 2048;
  u16* Vs = stage;

  const int tid = threadIdx.x;
  const int wv = tid >> 6, lane = tid & 63;
  const int quad = lane >> 4, l16 = lane & 15;
  const int lr = lane >> 2;
  const int lc = (((lane & 3) ^ ((lr >> 1) & 3)) * 8);  // swizzled chunk
  const int k3 = (l16 >> 1) & 3;                        // frag-read swizzle key
  const int qt = blockIdx.x >> 1, h = blockIdx.x & 1;
  const int w = blockIdx.y, b = blockIdx.z;
  const int s0 = w * 128;
  const size_t base2 = (size_t)b * SEQ * LDQ;   // qk buffer base
  const size_t base  = (size_t)b * SEQ * DM;    // output base
  const size_t btok  = (size_t)b * SEQ;
  const int qrow0 = s0 + qt * 64;

  f32x4 acc[16];
  #pragma unroll
  for (int i = 0; i < 16; ++i) acc[i] = (f32x4){0.f, 0.f, 0.f, 0.f};

  // ---- phase 1: scores ----
  for (int kk = 0; kk < DM; kk += 32) {
    #pragma unroll
    for (int j = 0; j < 5; ++j) {    // 20 issues: 4 Q + 16 K
      int e = wv * 5 + j;
      if (e < 4) {
        gload_lds16(QKb + base2 + (size_t)(qrow0 + e * 16 + lr) * LDQ + kk + lc, Qs + e * 512);
      } else {
        int f = e - 4;
        gload_lds16(QKb + DM + base2 + (size_t)(s0 + f * 16 + lr) * LDQ + kk + lc, Ks + f * 512);
      }
    }
    __syncthreads();
    bf16x8 aq = *(const bf16x8*)&Qs[(wv * 16 + l16) * 32 + (quad ^ k3) * 8];
    #pragma unroll
    for (int nt = 0; nt < 16; ++nt) {
      bf16x8 bk = *(const bf16x8*)&Ks[(nt * 16 + l16) * 32 + (quad ^ k3) * 8];
      acc[nt] = __builtin_amdgcn_mfma_f32_16x16x32_bf16(aq, bk, acc[nt], 0, 0, 0);
    }
    __syncthreads();
  }

  // ---- softmax (row quad*4+r of this wave's 16 rows; reduce across 16 lanes) ----
  float mx[4] = {-1e30f, -1e30f, -1e30f, -1e30f};
  float sm[4] = {0.f, 0.f, 0.f, 0.f};
  #pragma unroll
  for (int nt = 0; nt < 16; ++nt)
    #pragma unroll
    for (int r = 0; r < 4; ++r) {
      float s = acc[nt][r] * 0.125f;
      acc[nt][r] = s;
      mx[r] = fmaxf(mx[r], s);
    }
  #pragma unroll
  for (int r = 0; r < 4; ++r)
    #pragma unroll
    for (int off = 8; off > 0; off >>= 1)
      mx[r] = fmaxf(mx[r], __shfl_xor(mx[r], off, 64));
  #pragma unroll
  for (int nt = 0; nt < 16; ++nt)
    #pragma unroll
    for (int r = 0; r < 4; ++r) {
      float e = __expf(acc[nt][r] - mx[r]);
      acc[nt][r] = e;
      sm[r] += e;
    }
  #pragma unroll
  for (int r = 0; r < 4; ++r)
    #pragma unroll
    for (int off = 8; off > 0; off >>= 1)
      sm[r] += __shfl_xor(sm[r], off, 64);
  float inv[4];
  #pragma unroll
  for (int r = 0; r < 4; ++r) inv[r] = 1.f / sm[r];
  #pragma unroll
  for (int nt = 0; nt < 16; ++nt)
    #pragma unroll
    for (int r = 0; r < 4; ++r)
      Pbuf[(wv * 16 + quad * 4 + r) * PSTR + nt * 16 + l16] = f2b(acc[nt][r] * inv[r]);
  __syncthreads();

  // ---- phase 2: O = P * V  (M=64, K=256, this block's N-half = 2 slabs of 256) ----
  u16* op = ((w & 1) ? oB : oA) + base;
  for (int sl = 0; sl < 2; ++sl) {
    const int nb = (h * 2 + sl) * 256;
    f32x4 acc2[4][4];
    #pragma unroll
    for (int a = 0; a < 4; ++a)
      #pragma unroll
      for (int c = 0; c < 4; ++c) acc2[a][c] = (f32x4){0.f, 0.f, 0.f, 0.f};
    for (int ks = 0; ks < 8; ++ks) {
      #pragma unroll
      for (int j = 0; j < 4; ++j) {          // 16 issues: 256 d-rows x 32 tokens
        int e = wv * 4 + j;
        gload_lds16(Vt + (size_t)(nb + e * 16 + lr) * NTOK + btok + s0 + ks * 32 + lc, Vs + e * 512);
      }
      __syncthreads();
      bf16x8 af[4];
      #pragma unroll
      for (int mt = 0; mt < 4; ++mt)
        af[mt] = *(const bf16x8*)&Pbuf[(mt * 16 + l16) * PSTR + ks * 32 + quad * 8];
      #pragma unroll
      for (int u = 0; u < 4; ++u) {
        bf16x8 bb = *(const bf16x8*)&Vs[((wv * 4 + u) * 16 + l16) * 32 + (quad ^ k3) * 8];
        #pragma unroll
        for (int mt = 0; mt < 4; ++mt)
          acc2[mt][u] = __builtin_amdgcn_mfma_f32_16x16x32_bf16(af[mt], bb, acc2[mt][u], 0, 0, 0);
      }
      __syncthreads();
    }
    #pragma unroll
    for (int mt = 0; mt < 4; ++mt)
      #pragma unroll
      for (int u = 0; u < 4; ++u) {
        int row = qrow0 + mt * 16 + quad * 4;
        int col = nb + (wv * 4 + u) * 16 + l16;
        #pragma unroll
        for (int r = 0; r < 4; ++r)
          op[(size_t)(row + r) * DM + col] = f2b(acc2[mt][u][r]);
      }
  }
}

// ---------------- merge parity buffers -> bf16 (x8 vectorized) ----------------
__global__ __launch_bounds__(256) void k_norm(const u16* __restrict__ oA, const u16* __restrict__ oB,
                                              u16* __restrict__ out, int n8) {
  int i = blockIdx.x * 256 + threadIdx.x;
  if (i >= n8) return;
  int s = (i >> 7) & (SEQ - 1);     // 128 groups of 8 per token row
  uint4 a = ((const uint4*)oA)[i];
  uint4 r = a;
  if (s >= 128 && s < 3968) {       // interior: one even + one odd window
    uint4 bq = ((const uint4*)oB)[i];
    const unsigned* ap = (const unsigned*)&a;
    const unsigned* bp = (const unsigned*)&bq;
    unsigned* rp = (unsigned*)&r;
    #pragma unroll
    for (int k = 0; k < 4; ++k) {
      float lo = 0.5f * (b2f((u16)(ap[k] & 0xffff)) + b2f((u16)(bp[k] & 0xffff)));
      float hi = 0.5f * (b2f((u16)(ap[k] >> 16))    + b2f((u16)(bp[k] >> 16)));
      rp[k] = (unsigned)f2b(lo) | ((unsigned)f2b(hi) << 16);
    }
  }
  ((uint4*)out)[i] = r;
}

extern "C" void kernel_launch(void* const* d_in, const int* in_sizes, int n_in,
                              void* d_out, int out_size, void* d_ws, size_t ws_size,
                              hipStream_t stream) {
  const float* x  = (const float*)d_in[0];
  const float* Wq = (const float*)d_in[1];
  const float* bq = (const float*)d_in[2];
  const float* Wk = (const float*)d_in[3];
  const float* bk = (const float*)d_in[4];
  const float* Wv = (const float*)d_in[5];
  const float* bv = (const float*)d_in[6];
  const float* Wo = (const float*)d_in[7];
  const float* bo = (const float*)d_in[8];
  float* out = (float*)d_out;

  char* ws = (char*)d_ws;
  const size_t MB = 1024 * 1024;
  u16*   xb   = (u16*)(ws);                 // 32 MB: x bf16; later merged attn output
  u16*   qkb  = (u16*)(ws + 32 * MB);       // 64 MB: [tok][2048] q|k
  u16*   vtb  = (u16*)(ws + 96 * MB);       // 32 MB: V transposed [d][tok]
  u16*   wqt  = (u16*)(ws + 128 * MB);      // 8 MB: wqt|wkt|wvt|wot contiguous
  float* bcat = (float*)(ws + 136 * MB);    // 12 KB
  u16*   oA   = (u16*)(ws + 137 * MB);      // 32 MB
  u16*   oB   = (u16*)(ws + 169 * MB);      // 32 MB  (end: 201 MB)

  int n4tok = (int)((size_t)NTOK * DM / 4);
  k_convert<<<(n4tok + 255) / 256, 256, 0, stream>>>(x, xb, n4tok);
  k_transpose4<<<dim3(DM / 32, DM / 32, 4), dim3(32, 8), 0, stream>>>(Wq, Wk, Wv, Wo, wqt);
  k_catbias<<<12, 256, 0, stream>>>(bq, bk, bv, bcat);

  // fused QKV GEMM: N=3072 over [wqt|wkt|wvt]; q,k -> qkb row-major; v -> vtb transposed
  k_gemm<<<dim3(3 * DM / 128, NTOK / 128), 256, 0, stream>>>(
      xb, wqt, bcat, nullptr, qkb, 2048, vtb, 2048, NTOK, 3 * DM, DM);

  k_attn<<<dim3(8, NWIN, NBATCH), 256, 0, stream>>>(qkb, vtb, oA, oB);

  int n8tok = (int)((size_t)NTOK * DM / 8);
  k_norm<<<(n8tok + 255) / 256, 256, 0, stream>>>(oA, oB, xb, n8tok);

  u16* wot = wqt + 3 * (size_t)DM * DM;
  k_gemm<<<dim3(DM / 128, NTOK / 128), 256, 0, stream>>>(
      xb, wot, bo, out, nullptr, DM, nullptr, DM, NTOK, DM, DM);
}

// Round 6
// 376.860 us; speedup vs baseline: 1.6258x; 1.1330x over previous
//
#include <hip/hip_runtime.h>
#include <hip/hip_bf16.h>

typedef unsigned short u16;
typedef short bf16x8 __attribute__((ext_vector_type(8)));
typedef float f32x4 __attribute__((ext_vector_type(4)));
typedef float f32x16 __attribute__((ext_vector_type(16)));

#define DM     1024
#define SEQ    4096
#define NBATCH 4
#define NWIN   31
#define NTOK   16384   // NBATCH*SEQ

__device__ __forceinline__ u16 f2b(float f) {
  union { float f; unsigned u; } x; x.f = f;
  unsigned r = (x.u + 0x7fffu + ((x.u >> 16) & 1u)) >> 16;  // RNE
  return (u16)r;
}
__device__ __forceinline__ float b2f(u16 v) {
  union { unsigned u; float f; } x; x.u = ((unsigned)v) << 16; return x.f;
}
// async global->LDS, 16B per lane. lds dest is wave-uniform base + lane*16.
__device__ __forceinline__ void gload_lds16(const u16* g, u16* l) {
  __builtin_amdgcn_global_load_lds(
      (const __attribute__((address_space(1))) void*)g,
      (__attribute__((address_space(3))) void*)l, 16, 0, 0);
}

// ---------------- fp32 -> bf16 convert (x4 vectorized) ----------------
__global__ __launch_bounds__(256) void k_convert(const float* __restrict__ in,
                                                 u16* __restrict__ out, int n4) {
  int i = blockIdx.x * 256 + threadIdx.x;
  if (i >= n4) return;
  float4 v = ((const float4*)in)[i];
  ushort4 o; o.x = f2b(v.x); o.y = f2b(v.y); o.z = f2b(v.z); o.w = f2b(v.w);
  ((ushort4*)out)[i] = o;
}

// ---------------- 4x W (K x N fp32) -> Wt (N x K bf16), fused ----------------
__global__ __launch_bounds__(256) void k_transpose4(const float* __restrict__ W0,
                                                    const float* __restrict__ W1,
                                                    const float* __restrict__ W2,
                                                    const float* __restrict__ W3,
                                                    u16* __restrict__ Wt) {
  __shared__ float tile[32][33];
  int z = blockIdx.z;
  const float* W = (z == 0) ? W0 : (z == 1) ? W1 : (z == 2) ? W2 : W3;
  u16* dst = Wt + (size_t)z * DM * DM;
  int n0 = blockIdx.x * 32, k0 = blockIdx.y * 32;
  int tx = threadIdx.x, ty = threadIdx.y;
  #pragma unroll
  for (int i = ty; i < 32; i += 8) tile[i][tx] = W[(size_t)(k0 + i) * DM + n0 + tx];
  __syncthreads();
  #pragma unroll
  for (int i = ty; i < 32; i += 8) dst[(size_t)(n0 + i) * DM + k0 + tx] = f2b(tile[tx][i]);
}

// ---------------- concat bias [bq|bk|bv] -> 3072 ----------------
__global__ __launch_bounds__(256) void k_catbias(const float* __restrict__ bq,
                                                 const float* __restrict__ bk,
                                                 const float* __restrict__ bv,
                                                 float* __restrict__ o) {
  int i = blockIdx.x * 256 + threadIdx.x;
  if (i >= 3 * DM) return;
  float v = (i < DM) ? bq[i] : (i < 2 * DM) ? bk[i - DM] : bv[i - 2 * DM];
  o[i] = v;
}

// ---------------- bf16 MFMA GEMM: C[M,N] = A[M,K] * Bt[N,K]^T + bias ----------------
// 128x128 tile, 4 waves each 64x64 (2x2 of 32x32x16 MFMA), BK=64.
// XOR chunk swizzle with row-complete key ((row&7)+((row>>3)&7))&7: lanes 8 apart
// get distinct keys -> conflict-free b128 frag reads (round-5 key l31&7 collided).
__global__ __launch_bounds__(256, 4) void k_gemm(const u16* __restrict__ A, const u16* __restrict__ Bt,
                                                 const float* __restrict__ bias,
                                                 float* __restrict__ Cf,
                                                 u16* __restrict__ Cb, int ldc,
                                                 u16* __restrict__ Ct, int csplit,
                                                 int M, int N, int K) {
  __shared__ u16 As[128 * 64];
  __shared__ u16 Bs[128 * 64];
  const int tid = threadIdx.x;
  const int wv = tid >> 6, lane = tid & 63;
  const int l31 = lane & 31, hl = lane >> 5;
  const int l7 = lane & 7, lr8 = lane >> 3;
  const int kq = (l31 & 7) + (l31 >> 3);           // frag key base
  const int m0 = blockIdx.y * 128, n0 = blockIdx.x * 128;
  const int wm = (wv >> 1) * 64, wn = (wv & 1) * 64;
  f32x16 acc[2][2];
  #pragma unroll
  for (int a = 0; a < 2; ++a)
    #pragma unroll
    for (int b = 0; b < 2; ++b)
      #pragma unroll
      for (int r = 0; r < 16; ++r) acc[a][b][r] = 0.f;

  for (int kk = 0; kk < K; kk += 64) {
    #pragma unroll
    for (int j = 0; j < 4; ++j) {                  // A: 16 issues of 8 rows
      int e = wv * 4 + j;
      int lc = (l7 ^ ((lr8 + e) & 7)) * 8;
      gload_lds16(A + (size_t)(m0 + e * 8 + lr8) * K + kk + lc, As + e * 512);
    }
    #pragma unroll
    for (int j = 0; j < 4; ++j) {                  // B: 16 issues of 8 rows
      int e = wv * 4 + j;
      int lc = (l7 ^ ((lr8 + e) & 7)) * 8;
      gload_lds16(Bt + (size_t)(n0 + e * 8 + lr8) * K + kk + lc, Bs + e * 512);
    }
    __syncthreads();
    #pragma unroll
    for (int s = 0; s < 4; ++s) {                  // 4 k-steps of 16
      bf16x8 af[2], bfr[2];
      #pragma unroll
      for (int t = 0; t < 2; ++t)
        af[t]  = *(const bf16x8*)&As[(wm + t * 32 + l31) * 64 + (((2 * s + hl) ^ ((kq + 4 * t) & 7)) * 8)];
      #pragma unroll
      for (int t = 0; t < 2; ++t)
        bfr[t] = *(const bf16x8*)&Bs[(wn + t * 32 + l31) * 64 + (((2 * s + hl) ^ ((kq + 4 * t) & 7)) * 8)];
      #pragma unroll
      for (int mt = 0; mt < 2; ++mt)
        #pragma unroll
        for (int nt = 0; nt < 2; ++nt)
          acc[mt][nt] = __builtin_amdgcn_mfma_f32_32x32x16_bf16(af[mt], bfr[nt], acc[mt][nt], 0, 0, 0);
    }
    __syncthreads();
  }
  // D layout (32x32): col = lane&31, row = (reg&3) + 8*(reg>>2) + 4*(lane>>5)
  #pragma unroll
  for (int mt = 0; mt < 2; ++mt) {
    #pragma unroll
    for (int nt = 0; nt < 2; ++nt) {
      int col = n0 + wn + nt * 32 + l31;
      float bv = bias[col];
      #pragma unroll
      for (int g = 0; g < 4; ++g) {
        int row = m0 + wm + mt * 32 + g * 8 + hl * 4;
        if (Cf) {
          #pragma unroll
          for (int r = 0; r < 4; ++r)
            Cf[(size_t)(row + r) * N + col] = acc[mt][nt][g * 4 + r] + bv;
        } else if (col < csplit) {
          #pragma unroll
          for (int r = 0; r < 4; ++r)
            Cb[(size_t)(row + r) * ldc + col] = f2b(acc[mt][nt][g * 4 + r] + bv);
        } else {
          ushort4 o;
          o.x = f2b(acc[mt][nt][g * 4 + 0] + bv); o.y = f2b(acc[mt][nt][g * 4 + 1] + bv);
          o.z = f2b(acc[mt][nt][g * 4 + 2] + bv); o.w = f2b(acc[mt][nt][g * 4 + 3] + bv);
          *(ushort4*)&Ct[(size_t)(col - csplit) * M + row] = o;
        }
      }
    }
  }
}

// ---------------- windowed attention (restructured) ----------------
// Flat grid 512, XCD-swizzled: the 4 q-subtile blocks of a (w,b) window share id%8
// -> same XCD L2 for the shared K/V reads. Block = 256 thr = 4 waves, LDS 74 KB
// -> 2 blocks/CU (grid 496 ~ 1.94/CU).
// Phase 1 (no duplication): S = Q*K^T/8, each wave owns a 64-key slab for all 64 q
// (4 Q-frags + 4 K-frags per 16 MFMA -> half the LDS reads of the old layout), BK=64.
// Softmax: in-wave shfl partials + tiny LDS table across the 4 waves.
// Phase 2: O = P*V via Vt [d][tok]; wave owns 64 output dims per 256-slab.
// All LDS tiles use the row-complete XOR chunk swizzle; Pbuf is 256-stride with
// key q&7 (written scalar, read as b128 A-frags).
#define LDQ  2048
__global__ __launch_bounds__(256, 2) void k_attn(const u16* __restrict__ QKb, const u16* __restrict__ Vt,
                                                 u16* __restrict__ oA, u16* __restrict__ oB) {
  __shared__ u16 stage[20480];     // Qs 64x64 (8KB) + Ks 256x64 (32KB); reused as Vs 256x64
  __shared__ u16 Pbuf[64 * 256];   // 32KB
  __shared__ float red[2][4][64];  // cross-wave softmax partials (max, sum)
  u16* Qs = stage;
  u16* Ks = stage + 4096;
  u16* Vs = stage;

  const int tid = threadIdx.x;
  const int wv = tid >> 6, lane = tid & 63;
  const int quad = lane >> 4, l16 = lane & 15;
  const int l7 = lane & 7, lr8 = lane >> 3;
  const int kq = (l16 & 7) + (l16 >> 3);           // frag key base (rows = 16t + l16)

  // decode swizzled flat grid: id = (pair&7) + 8*(qt + 4*(pair>>3)), pair = w + 31*b
  int id = blockIdx.x;
  int s_ = id >> 3;
  int qt = s_ & 3;
  int pair = (s_ >> 2) * 8 + (id & 7);
  if (pair >= NWIN * NBATCH) return;
  int b = pair / NWIN, w = pair - NWIN * b;

  const int s0 = w * 128;
  const size_t base2 = (size_t)b * SEQ * LDQ;
  const size_t base  = (size_t)b * SEQ * DM;
  const size_t btok  = (size_t)b * SEQ;
  const int qrow0 = s0 + qt * 64;

  f32x4 acc[4][4];   // S[q = mt*16+quad*4+r][key = wv*64 + nt*16 + l16]
  #pragma unroll
  for (int mt = 0; mt < 4; ++mt)
    #pragma unroll
    for (int nt = 0; nt < 4; ++nt) acc[mt][nt] = (f32x4){0.f, 0.f, 0.f, 0.f};

  // ---- phase 1: scores, BK=64 ----
  for (int kk = 0; kk < DM; kk += 64) {
    #pragma unroll
    for (int j = 0; j < 10; ++j) {   // 40 issues: 8 Q + 32 K
      int idx = wv * 10 + j;
      if (idx < 8) {
        int lc = (l7 ^ ((lr8 + idx) & 7)) * 8;
        gload_lds16(QKb + base2 + (size_t)(qrow0 + idx * 8 + lr8) * LDQ + kk + lc, Qs + idx * 512);
      } else {
        int f = idx - 8;
        int lc = (l7 ^ ((lr8 + f) & 7)) * 8;
        gload_lds16(QKb + DM + base2 + (size_t)(s0 + f * 8 + lr8) * LDQ + kk + lc, Ks + f * 512);
      }
    }
    __syncthreads();
    #pragma unroll
    for (int s2 = 0; s2 < 2; ++s2) {
      bf16x8 aq[4], bk[4];
      #pragma unroll
      for (int mt = 0; mt < 4; ++mt)
        aq[mt] = *(const bf16x8*)&Qs[(mt * 16 + l16) * 64 + (((s2 * 4 + quad) ^ ((kq + 2 * mt) & 7)) * 8)];
      #pragma unroll
      for (int nt = 0; nt < 4; ++nt)
        bk[nt] = *(const bf16x8*)&Ks[(wv * 64 + nt * 16 + l16) * 64 + (((s2 * 4 + quad) ^ ((kq + 2 * nt) & 7)) * 8)];
      #pragma unroll
      for (int mt = 0; mt < 4; ++mt)
        #pragma unroll
        for (int nt = 0; nt < 4; ++nt)
          acc[mt][nt] = __builtin_amdgcn_mfma_f32_16x16x32_bf16(aq[mt], bk[nt], acc[mt][nt], 0, 0, 0);
    }
    __syncthreads();
  }

  // ---- softmax over 256 keys: wave partials (64 keys) + cross-wave LDS combine ----
  float mx[4][4], sm[4][4];
  #pragma unroll
  for (int mt = 0; mt < 4; ++mt)
    #pragma unroll
    for (int r = 0; r < 4; ++r) mx[mt][r] = -1e30f;
  #pragma unroll
  for (int mt = 0; mt < 4; ++mt)
    #pragma unroll
    for (int nt = 0; nt < 4; ++nt)
      #pragma unroll
      for (int r = 0; r < 4; ++r) {
        float v = acc[mt][nt][r] * 0.125f;
        acc[mt][nt][r] = v;
        mx[mt][r] = fmaxf(mx[mt][r], v);
      }
  #pragma unroll
  for (int mt = 0; mt < 4; ++mt)
    #pragma unroll
    for (int r = 0; r < 4; ++r)
      #pragma unroll
      for (int off = 8; off > 0; off >>= 1)
        mx[mt][r] = fmaxf(mx[mt][r], __shfl_xor(mx[mt][r], off, 64));
  if (l16 == 0) {
    #pragma unroll
    for (int mt = 0; mt < 4; ++mt)
      #pragma unroll
      for (int r = 0; r < 4; ++r)
        red[0][wv][mt * 16 + quad * 4 + r] = mx[mt][r];
  }
  __syncthreads();
  float gm[4][4];
  #pragma unroll
  for (int mt = 0; mt < 4; ++mt)
    #pragma unroll
    for (int r = 0; r < 4; ++r) {
      int q = mt * 16 + quad * 4 + r;
      gm[mt][r] = fmaxf(fmaxf(red[0][0][q], red[0][1][q]), fmaxf(red[0][2][q], red[0][3][q]));
      sm[mt][r] = 0.f;
    }
  #pragma unroll
  for (int mt = 0; mt < 4; ++mt)
    #pragma unroll
    for (int nt = 0; nt < 4; ++nt)
      #pragma unroll
      for (int r = 0; r < 4; ++r) {
        float e = __expf(acc[mt][nt][r] - gm[mt][r]);
        acc[mt][nt][r] = e;
        sm[mt][r] += e;
      }
  #pragma unroll
  for (int mt = 0; mt < 4; ++mt)
    #pragma unroll
    for (int r = 0; r < 4; ++r)
      #pragma unroll
      for (int off = 8; off > 0; off >>= 1)
        sm[mt][r] += __shfl_xor(sm[mt][r], off, 64);
  if (l16 == 0) {
    #pragma unroll
    for (int mt = 0; mt < 4; ++mt)
      #pragma unroll
      for (int r = 0; r < 4; ++r)
        red[1][wv][mt * 16 + quad * 4 + r] = sm[mt][r];
  }
  __syncthreads();
  // normalize and write P (chunk-swizzled by q&7)
  #pragma unroll
  for (int mt = 0; mt < 4; ++mt)
    #pragma unroll
    for (int r = 0; r < 4; ++r) {
      int q = mt * 16 + quad * 4 + r;
      float inv = 1.f / (red[1][0][q] + red[1][1][q] + red[1][2][q] + red[1][3][q]);
      #pragma unroll
      for (int nt = 0; nt < 4; ++nt) {
        int ke = wv * 64 + nt * 16 + l16;
        int phys = (ke >> 3) ^ (q & 7);
        Pbuf[q * 256 + phys * 8 + (ke & 7)] = f2b(acc[mt][nt][r] * inv);
      }
    }
  __syncthreads();

  // ---- phase 2: O = P * V (M=64, K=256, N=1024 in 4 slabs; 64-token V steps) ----
  u16* op = ((w & 1) ? oB : oA) + base;
  for (int slab = 0; slab < 4; ++slab) {
    const int nb = slab * 256;
    f32x4 acc2[4][4];   // [mt][u]: rows q, cols nb + wv*64 + u*16 + l16
    #pragma unroll
    for (int mt = 0; mt < 4; ++mt)
      #pragma unroll
      for (int u = 0; u < 4; ++u) acc2[mt][u] = (f32x4){0.f, 0.f, 0.f, 0.f};
    for (int sk = 0; sk < 4; ++sk) {
      const int tok0 = sk * 64;
      #pragma unroll
      for (int j = 0; j < 8; ++j) {      // 32 issues: 256 d-rows x 64 tokens
        int e = wv * 8 + j;
        int lc = (l7 ^ ((lr8 + e) & 7)) * 8;
        gload_lds16(Vt + (size_t)(nb + e * 8 + lr8) * NTOK + btok + s0 + tok0 + lc, Vs + e * 512);
      }
      __syncthreads();
      #pragma unroll
      for (int s2 = 0; s2 < 2; ++s2) {
        bf16x8 af[4];
        #pragma unroll
        for (int mt = 0; mt < 4; ++mt) {
          int cP = sk * 8 + s2 * 4 + quad;             // logical chunk in 0..31
          int phys = cP ^ (l16 & 7);
          af[mt] = *(const bf16x8*)&Pbuf[(mt * 16 + l16) * 256 + phys * 8];
        }
        #pragma unroll
        for (int u = 0; u < 4; ++u) {
          bf16x8 bb = *(const bf16x8*)&Vs[(wv * 64 + u * 16 + l16) * 64 +
                                          (((s2 * 4 + quad) ^ ((kq + 2 * u) & 7)) * 8)];
          #pragma unroll
          for (int mt = 0; mt < 4; ++mt)
            acc2[mt][u] = __builtin_amdgcn_mfma_f32_16x16x32_bf16(af[mt], bb, acc2[mt][u], 0, 0, 0);
        }
      }
      __syncthreads();
    }
    #pragma unroll
    for (int mt = 0; mt < 4; ++mt)
      #pragma unroll
      for (int u = 0; u < 4; ++u) {
        int row = qrow0 + mt * 16 + quad * 4;
        int col = nb + wv * 64 + u * 16 + l16;
        #pragma unroll
        for (int r = 0; r < 4; ++r)
          op[(size_t)(row + r) * DM + col] = f2b(acc2[mt][u][r]);
      }
  }
}

// ---------------- merge parity buffers -> bf16 (x8 vectorized) ----------------
__global__ __launch_bounds__(256) void k_norm(const u16* __restrict__ oA, const u16* __restrict__ oB,
                                              u16* __restrict__ out, int n8) {
  int i = blockIdx.x * 256 + threadIdx.x;
  if (i >= n8) return;
  int s = (i >> 7) & (SEQ - 1);     // 128 groups of 8 per token row
  uint4 a = ((const uint4*)oA)[i];
  uint4 r = a;
  if (s >= 128 && s < 3968) {       // interior: one even + one odd window
    uint4 bq = ((const uint4*)oB)[i];
    const unsigned* ap = (const unsigned*)&a;
    const unsigned* bp = (const unsigned*)&bq;
    unsigned* rp = (unsigned*)&r;
    #pragma unroll
    for (int k = 0; k < 4; ++k) {
      float lo = 0.5f * (b2f((u16)(ap[k] & 0xffff)) + b2f((u16)(bp[k] & 0xffff)));
      float hi = 0.5f * (b2f((u16)(ap[k] >> 16))    + b2f((u16)(bp[k] >> 16)));
      rp[k] = (unsigned)f2b(lo) | ((unsigned)f2b(hi) << 16);
    }
  }
  ((uint4*)out)[i] = r;
}

extern "C" void kernel_launch(void* const* d_in, const int* in_sizes, int n_in,
                              void* d_out, int out_size, void* d_ws, size_t ws_size,
                              hipStream_t stream) {
  const float* x  = (const float*)d_in[0];
  const float* Wq = (const float*)d_in[1];
  const float* bq = (const float*)d_in[2];
  const float* Wk = (const float*)d_in[3];
  const float* bk = (const float*)d_in[4];
  const float* Wv = (const float*)d_in[5];
  const float* bv = (const float*)d_in[6];
  const float* Wo = (const float*)d_in[7];
  const float* bo = (const float*)d_in[8];
  float* out = (float*)d_out;

  char* ws = (char*)d_ws;
  const size_t MB = 1024 * 1024;
  u16*   xb   = (u16*)(ws);                 // 32 MB: x bf16; later merged attn output
  u16*   qkb  = (u16*)(ws + 32 * MB);       // 64 MB: [tok][2048] q|k
  u16*   vtb  = (u16*)(ws + 96 * MB);       // 32 MB: V transposed [d][tok]
  u16*   wqt  = (u16*)(ws + 128 * MB);      // 8 MB: wqt|wkt|wvt|wot contiguous
  float* bcat = (float*)(ws + 136 * MB);    // 12 KB
  u16*   oA   = (u16*)(ws + 137 * MB);      // 32 MB
  u16*   oB   = (u16*)(ws + 169 * MB);      // 32 MB  (end: 201 MB)

  int n4tok = (int)((size_t)NTOK * DM / 4);
  k_convert<<<(n4tok + 255) / 256, 256, 0, stream>>>(x, xb, n4tok);
  k_transpose4<<<dim3(DM / 32, DM / 32, 4), dim3(32, 8), 0, stream>>>(Wq, Wk, Wv, Wo, wqt);
  k_catbias<<<12, 256, 0, stream>>>(bq, bk, bv, bcat);

  // fused QKV GEMM: N=3072 over [wqt|wkt|wvt]; q,k -> qkb row-major; v -> vtb transposed
  k_gemm<<<dim3(3 * DM / 128, NTOK / 128), 256, 0, stream>>>(
      xb, wqt, bcat, nullptr, qkb, 2048, vtb, 2048, NTOK, 3 * DM, DM);

  k_attn<<<512, 256, 0, stream>>>(qkb, vtb, oA, oB);

  int n8tok = (int)((size_t)NTOK * DM / 8);
  k_norm<<<(n8tok + 255) / 256, 256, 0, stream>>>(oA, oB, xb, n8tok);

  u16* wot = wqt + 3 * (size_t)DM * DM;
  k_gemm<<<dim3(DM / 128, NTOK / 128), 256, 0, stream>>>(
      xb, wot, bo, out, nullptr, DM, nullptr, DM, NTOK, DM, DM);
}

// Round 7
// 363.400 us; speedup vs baseline: 1.6860x; 1.0370x over previous
//
#include <hip/hip_runtime.h>
#include <hip/hip_bf16.h>

typedef unsigned short u16;
typedef short bf16x8 __attribute__((ext_vector_type(8)));
typedef float f32x4 __attribute__((ext_vector_type(4)));

#define DM     1024
#define SEQ    4096
#define NBATCH 4
#define NWIN   31
#define NTOK   16384   // NBATCH*SEQ

__device__ __forceinline__ u16 f2b(float f) {
  union { float f; unsigned u; } x; x.f = f;
  unsigned r = (x.u + 0x7fffu + ((x.u >> 16) & 1u)) >> 16;  // RNE
  return (u16)r;
}
__device__ __forceinline__ float b2f(u16 v) {
  union { unsigned u; float f; } x; x.u = ((unsigned)v) << 16; return x.f;
}
// async global->LDS, 16B per lane. lds dest is wave-uniform base + lane*16.
__device__ __forceinline__ void gload_lds16(const u16* g, u16* l) {
  __builtin_amdgcn_global_load_lds(
      (const __attribute__((address_space(1))) void*)g,
      (__attribute__((address_space(3))) void*)l, 16, 0, 0);
}

// ---------------- fp32 -> bf16 convert (x4 vectorized) ----------------
__global__ __launch_bounds__(256) void k_convert(const float* __restrict__ in,
                                                 u16* __restrict__ out, int n4) {
  int i = blockIdx.x * 256 + threadIdx.x;
  if (i >= n4) return;
  float4 v = ((const float4*)in)[i];
  ushort4 o; o.x = f2b(v.x); o.y = f2b(v.y); o.z = f2b(v.z); o.w = f2b(v.w);
  ((ushort4*)out)[i] = o;
}

// ---------------- 4x W (K x N fp32) -> Wt (N x K bf16), fused ----------------
__global__ __launch_bounds__(256) void k_transpose4(const float* __restrict__ W0,
                                                    const float* __restrict__ W1,
                                                    const float* __restrict__ W2,
                                                    const float* __restrict__ W3,
                                                    u16* __restrict__ Wt) {
  __shared__ float tile[32][33];
  int z = blockIdx.z;
  const float* W = (z == 0) ? W0 : (z == 1) ? W1 : (z == 2) ? W2 : W3;
  u16* dst = Wt + (size_t)z * DM * DM;
  int n0 = blockIdx.x * 32, k0 = blockIdx.y * 32;
  int tx = threadIdx.x, ty = threadIdx.y;
  #pragma unroll
  for (int i = ty; i < 32; i += 8) tile[i][tx] = W[(size_t)(k0 + i) * DM + n0 + tx];
  __syncthreads();
  #pragma unroll
  for (int i = ty; i < 32; i += 8) dst[(size_t)(n0 + i) * DM + k0 + tx] = f2b(tile[tx][i]);
}

// ---------------- concat bias [bq|bk|bv] -> 3072 ----------------
__global__ __launch_bounds__(256) void k_catbias(const float* __restrict__ bq,
                                                 const float* __restrict__ bk,
                                                 const float* __restrict__ bv,
                                                 float* __restrict__ o) {
  int i = blockIdx.x * 256 + threadIdx.x;
  if (i >= 3 * DM) return;
  float v = (i < DM) ? bq[i] : (i < 2 * DM) ? bk[i - DM] : bv[i - 2 * DM];
  o[i] = v;
}

// ---------------- bf16 MFMA GEMM: C[M,N] = A[M,K] * Bt[N,K]^T + bias ----------------
// 128x128 tile, 4 waves each 64x64 (4x4 of 16x16x32 MFMA), BK=64.
// Round-4 frag pattern (HW-verified 0 bank conflicts: key l16&7, quad-period XOR;
// the 32x32 l31-period variants measure +4cyc/ds_read_b128 — see R5/R6 post-mortem)
// + launch_bounds(256,4) (R5-verified VALU fix).
__global__ __launch_bounds__(256, 4) void k_gemm(const u16* __restrict__ A, const u16* __restrict__ Bt,
                                                 const float* __restrict__ bias,
                                                 float* __restrict__ Cf,
                                                 u16* __restrict__ Cb, int ldc,
                                                 u16* __restrict__ Ct, int csplit,
                                                 int M, int N, int K) {
  __shared__ u16 As[128 * 64];
  __shared__ u16 Bs[128 * 64];
  const int tid = threadIdx.x;
  const int wv = tid >> 6, lane = tid & 63;
  const int quad = lane >> 4, l16 = lane & 15;
  const int lr8 = lane >> 3;                       // staging: row within 8-row issue
  const int lc8 = (((lane & 7) ^ (lr8 & 7)) * 8);  // staging: swizzled chunk
  const int m0 = blockIdx.y * 128, n0 = blockIdx.x * 128;
  const int wm = (wv >> 1) * 64, wn = (wv & 1) * 64;
  const int k7 = l16 & 7;                          // frag-read swizzle key
  f32x4 acc[4][4];
  #pragma unroll
  for (int a = 0; a < 4; ++a)
    #pragma unroll
    for (int b = 0; b < 4; ++b) acc[a][b] = (f32x4){0.f, 0.f, 0.f, 0.f};

  for (int kk = 0; kk < K; kk += 64) {
    #pragma unroll
    for (int j = 0; j < 4; ++j) {                  // A: 16 issues of 8 rows
      int e = wv * 4 + j;
      gload_lds16(A + (size_t)(m0 + e * 8 + lr8) * K + kk + lc8, As + e * 512);
    }
    #pragma unroll
    for (int j = 0; j < 4; ++j) {                  // B: 16 issues of 8 rows
      int e = wv * 4 + j;
      gload_lds16(Bt + (size_t)(n0 + e * 8 + lr8) * K + kk + lc8, Bs + e * 512);
    }
    __syncthreads();
    #pragma unroll
    for (int h = 0; h < 2; ++h) {
      bf16x8 af[4], bfr[4];
      #pragma unroll
      for (int t = 0; t < 4; ++t)
        af[t]  = *(const bf16x8*)&As[(wm + t * 16 + l16) * 64 + ((h * 4 + quad) ^ k7) * 8];
      #pragma unroll
      for (int t = 0; t < 4; ++t)
        bfr[t] = *(const bf16x8*)&Bs[(wn + t * 16 + l16) * 64 + ((h * 4 + quad) ^ k7) * 8];
      #pragma unroll
      for (int mt = 0; mt < 4; ++mt)
        #pragma unroll
        for (int nt = 0; nt < 4; ++nt)
          acc[mt][nt] = __builtin_amdgcn_mfma_f32_16x16x32_bf16(af[mt], bfr[nt], acc[mt][nt], 0, 0, 0);
    }
    __syncthreads();
  }
  #pragma unroll
  for (int mt = 0; mt < 4; ++mt) {
    #pragma unroll
    for (int nt = 0; nt < 4; ++nt) {
      int row = m0 + wm + mt * 16 + quad * 4;   // D: row=(lane>>4)*4+reg, col=lane&15
      int col = n0 + wn + nt * 16 + l16;
      float bv = bias[col];
      if (Cf) {
        #pragma unroll
        for (int r = 0; r < 4; ++r)
          Cf[(size_t)(row + r) * N + col] = acc[mt][nt][r] + bv;
      } else if (col < csplit) {
        #pragma unroll
        for (int r = 0; r < 4; ++r)
          Cb[(size_t)(row + r) * ldc + col] = f2b(acc[mt][nt][r] + bv);
      } else {
        ushort4 o;
        o.x = f2b(acc[mt][nt][0] + bv); o.y = f2b(acc[mt][nt][1] + bv);
        o.z = f2b(acc[mt][nt][2] + bv); o.w = f2b(acc[mt][nt][3] + bv);
        *(ushort4*)&Ct[(size_t)(col - csplit) * M + row] = o;
      }
    }
  }
}

// ---------------- windowed attention ----------------
// Flat grid 512, XCD-swizzled; block 256 = 4 waves; LDS 74 KB -> 2 blocks/CU.
// Phase 1: S = Q*K^T/8, wave owns a 64-key slab for all 64 q, BK=64.
// Softmax: in-wave shfl + cross-wave LDS combine.
// Phase 2: O = P*V via Vt [d][tok]; parity-buffer stores (no atomics).
#define LDQ  2048
__global__ __launch_bounds__(256, 2) void k_attn(const u16* __restrict__ QKb, const u16* __restrict__ Vt,
                                                 u16* __restrict__ oA, u16* __restrict__ oB) {
  __shared__ u16 stage[20480];     // Qs 64x64 (8KB) + Ks 256x64 (32KB); reused as Vs 256x64
  __shared__ u16 Pbuf[64 * 256];   // 32KB
  __shared__ float red[2][4][64];  // cross-wave softmax partials (max, sum)
  u16* Qs = stage;
  u16* Ks = stage + 4096;
  u16* Vs = stage;

  const int tid = threadIdx.x;
  const int wv = tid >> 6, lane = tid & 63;
  const int quad = lane >> 4, l16 = lane & 15;
  const int l7 = lane & 7, lr8 = lane >> 3;
  const int kq = (l16 & 7) + (l16 >> 3);           // frag key base (rows = 16t + l16)

  // decode swizzled flat grid: id = (pair&7) + 8*(qt + 4*(pair>>3)), pair = w + 31*b
  int id = blockIdx.x;
  int s_ = id >> 3;
  int qt = s_ & 3;
  int pair = (s_ >> 2) * 8 + (id & 7);
  if (pair >= NWIN * NBATCH) return;
  int b = pair / NWIN, w = pair - NWIN * b;

  const int s0 = w * 128;
  const size_t base2 = (size_t)b * SEQ * LDQ;
  const size_t base  = (size_t)b * SEQ * DM;
  const size_t btok  = (size_t)b * SEQ;
  const int qrow0 = s0 + qt * 64;

  f32x4 acc[4][4];   // S[q = mt*16+quad*4+r][key = wv*64 + nt*16 + l16]
  #pragma unroll
  for (int mt = 0; mt < 4; ++mt)
    #pragma unroll
    for (int nt = 0; nt < 4; ++nt) acc[mt][nt] = (f32x4){0.f, 0.f, 0.f, 0.f};

  // ---- phase 1: scores, BK=64 ----
  for (int kk = 0; kk < DM; kk += 64) {
    #pragma unroll
    for (int j = 0; j < 10; ++j) {   // 40 issues: 8 Q + 32 K
      int idx = wv * 10 + j;
      if (idx < 8) {
        int lc = (l7 ^ ((lr8 + idx) & 7)) * 8;
        gload_lds16(QKb + base2 + (size_t)(qrow0 + idx * 8 + lr8) * LDQ + kk + lc, Qs + idx * 512);
      } else {
        int f = idx - 8;
        int lc = (l7 ^ ((lr8 + f) & 7)) * 8;
        gload_lds16(QKb + DM + base2 + (size_t)(s0 + f * 8 + lr8) * LDQ + kk + lc, Ks + f * 512);
      }
    }
    __syncthreads();
    #pragma unroll
    for (int s2 = 0; s2 < 2; ++s2) {
      bf16x8 aq[4], bk[4];
      #pragma unroll
      for (int mt = 0; mt < 4; ++mt)
        aq[mt] = *(const bf16x8*)&Qs[(mt * 16 + l16) * 64 + (((s2 * 4 + quad) ^ ((kq + 2 * mt) & 7)) * 8)];
      #pragma unroll
      for (int nt = 0; nt < 4; ++nt)
        bk[nt] = *(const bf16x8*)&Ks[(wv * 64 + nt * 16 + l16) * 64 + (((s2 * 4 + quad) ^ ((kq + 2 * nt) & 7)) * 8)];
      #pragma unroll
      for (int mt = 0; mt < 4; ++mt)
        #pragma unroll
        for (int nt = 0; nt < 4; ++nt)
          acc[mt][nt] = __builtin_amdgcn_mfma_f32_16x16x32_bf16(aq[mt], bk[nt], acc[mt][nt], 0, 0, 0);
    }
    __syncthreads();
  }

  // ---- softmax over 256 keys ----
  float mx[4][4], sm[4][4];
  #pragma unroll
  for (int mt = 0; mt < 4; ++mt)
    #pragma unroll
    for (int r = 0; r < 4; ++r) mx[mt][r] = -1e30f;
  #pragma unroll
  for (int mt = 0; mt < 4; ++mt)
    #pragma unroll
    for (int nt = 0; nt < 4; ++nt)
      #pragma unroll
      for (int r = 0; r < 4; ++r) {
        float v = acc[mt][nt][r] * 0.125f;
        acc[mt][nt][r] = v;
        mx[mt][r] = fmaxf(mx[mt][r], v);
      }
  #pragma unroll
  for (int mt = 0; mt < 4; ++mt)
    #pragma unroll
    for (int r = 0; r < 4; ++r)
      #pragma unroll
      for (int off = 8; off > 0; off >>= 1)
        mx[mt][r] = fmaxf(mx[mt][r], __shfl_xor(mx[mt][r], off, 64));
  if (l16 == 0) {
    #pragma unroll
    for (int mt = 0; mt < 4; ++mt)
      #pragma unroll
      for (int r = 0; r < 4; ++r)
        red[0][wv][mt * 16 + quad * 4 + r] = mx[mt][r];
  }
  __syncthreads();
  float gm[4][4];
  #pragma unroll
  for (int mt = 0; mt < 4; ++mt)
    #pragma unroll
    for (int r = 0; r < 4; ++r) {
      int q = mt * 16 + quad * 4 + r;
      gm[mt][r] = fmaxf(fmaxf(red[0][0][q], red[0][1][q]), fmaxf(red[0][2][q], red[0][3][q]));
      sm[mt][r] = 0.f;
    }
  #pragma unroll
  for (int mt = 0; mt < 4; ++mt)
    #pragma unroll
    for (int nt = 0; nt < 4; ++nt)
      #pragma unroll
      for (int r = 0; r < 4; ++r) {
        float e = __expf(acc[mt][nt][r] - gm[mt][r]);
        acc[mt][nt][r] = e;
        sm[mt][r] += e;
      }
  #pragma unroll
  for (int mt = 0; mt < 4; ++mt)
    #pragma unroll
    for (int r = 0; r < 4; ++r)
      #pragma unroll
      for (int off = 8; off > 0; off >>= 1)
        sm[mt][r] += __shfl_xor(sm[mt][r], off, 64);
  if (l16 == 0) {
    #pragma unroll
    for (int mt = 0; mt < 4; ++mt)
      #pragma unroll
      for (int r = 0; r < 4; ++r)
        red[1][wv][mt * 16 + quad * 4 + r] = sm[mt][r];
  }
  __syncthreads();
  // normalize and write P (chunk-swizzled by q&7)
  #pragma unroll
  for (int mt = 0; mt < 4; ++mt)
    #pragma unroll
    for (int r = 0; r < 4; ++r) {
      int q = mt * 16 + quad * 4 + r;
      float inv = 1.f / (red[1][0][q] + red[1][1][q] + red[1][2][q] + red[1][3][q]);
      #pragma unroll
      for (int nt = 0; nt < 4; ++nt) {
        int ke = wv * 64 + nt * 16 + l16;
        int phys = (ke >> 3) ^ (q & 7);
        Pbuf[q * 256 + phys * 8 + (ke & 7)] = f2b(acc[mt][nt][r] * inv);
      }
    }
  __syncthreads();

  // ---- phase 2: O = P * V (M=64, K=256, N=1024 in 4 slabs; 64-token V steps) ----
  u16* op = ((w & 1) ? oB : oA) + base;
  for (int slab = 0; slab < 4; ++slab) {
    const int nb = slab * 256;
    f32x4 acc2[4][4];   // [mt][u]: rows q, cols nb + wv*64 + u*16 + l16
    #pragma unroll
    for (int mt = 0; mt < 4; ++mt)
      #pragma unroll
      for (int u = 0; u < 4; ++u) acc2[mt][u] = (f32x4){0.f, 0.f, 0.f, 0.f};
    for (int sk = 0; sk < 4; ++sk) {
      const int tok0 = sk * 64;
      #pragma unroll
      for (int j = 0; j < 8; ++j) {      // 32 issues: 256 d-rows x 64 tokens
        int e = wv * 8 + j;
        int lc = (l7 ^ ((lr8 + e) & 7)) * 8;
        gload_lds16(Vt + (size_t)(nb + e * 8 + lr8) * NTOK + btok + s0 + tok0 + lc, Vs + e * 512);
      }
      __syncthreads();
      #pragma unroll
      for (int s2 = 0; s2 < 2; ++s2) {
        bf16x8 af[4];
        #pragma unroll
        for (int mt = 0; mt < 4; ++mt) {
          int cP = sk * 8 + s2 * 4 + quad;             // logical chunk in 0..31
          int phys = cP ^ (l16 & 7);
          af[mt] = *(const bf16x8*)&Pbuf[(mt * 16 + l16) * 256 + phys * 8];
        }
        #pragma unroll
        for (int u = 0; u < 4; ++u) {
          bf16x8 bb = *(const bf16x8*)&Vs[(wv * 64 + u * 16 + l16) * 64 +
                                          (((s2 * 4 + quad) ^ ((kq + 2 * u) & 7)) * 8)];
          #pragma unroll
          for (int mt = 0; mt < 4; ++mt)
            acc2[mt][u] = __builtin_amdgcn_mfma_f32_16x16x32_bf16(af[mt], bb, acc2[mt][u], 0, 0, 0);
        }
      }
      __syncthreads();
    }
    #pragma unroll
    for (int mt = 0; mt < 4; ++mt)
      #pragma unroll
      for (int u = 0; u < 4; ++u) {
        int row = qrow0 + mt * 16 + quad * 4;
        int col = nb + wv * 64 + u * 16 + l16;
        #pragma unroll
        for (int r = 0; r < 4; ++r)
          op[(size_t)(row + r) * DM + col] = f2b(acc2[mt][u][r]);
      }
  }
}

// ---------------- merge parity buffers -> bf16 (x8 vectorized) ----------------
__global__ __launch_bounds__(256) void k_norm(const u16* __restrict__ oA, const u16* __restrict__ oB,
                                              u16* __restrict__ out, int n8) {
  int i = blockIdx.x * 256 + threadIdx.x;
  if (i >= n8) return;
  int s = (i >> 7) & (SEQ - 1);     // 128 groups of 8 per token row
  uint4 a = ((const uint4*)oA)[i];
  uint4 r = a;
  if (s >= 128 && s < 3968) {       // interior: one even + one odd window
    uint4 bq = ((const uint4*)oB)[i];
    const unsigned* ap = (const unsigned*)&a;
    const unsigned* bp = (const unsigned*)&bq;
    unsigned* rp = (unsigned*)&r;
    #pragma unroll
    for (int k = 0; k < 4; ++k) {
      float lo = 0.5f * (b2f((u16)(ap[k] & 0xffff)) + b2f((u16)(bp[k] & 0xffff)));
      float hi = 0.5f * (b2f((u16)(ap[k] >> 16))    + b2f((u16)(bp[k] >> 16)));
      rp[k] = (unsigned)f2b(lo) | ((unsigned)f2b(hi) << 16);
    }
  }
  ((uint4*)out)[i] = r;
}

extern "C" void kernel_launch(void* const* d_in, const int* in_sizes, int n_in,
                              void* d_out, int out_size, void* d_ws, size_t ws_size,
                              hipStream_t stream) {
  const float* x  = (const float*)d_in[0];
  const float* Wq = (const float*)d_in[1];
  const float* bq = (const float*)d_in[2];
  const float* Wk = (const float*)d_in[3];
  const float* bk = (const float*)d_in[4];
  const float* Wv = (const float*)d_in[5];
  const float* bv = (const float*)d_in[6];
  const float* Wo = (const float*)d_in[7];
  const float* bo = (const float*)d_in[8];
  float* out = (float*)d_out;

  char* ws = (char*)d_ws;
  const size_t MB = 1024 * 1024;
  u16*   xb   = (u16*)(ws);                 // 32 MB: x bf16; later merged attn output
  u16*   qkb  = (u16*)(ws + 32 * MB);       // 64 MB: [tok][2048] q|k
  u16*   vtb  = (u16*)(ws + 96 * MB);       // 32 MB: V transposed [d][tok]
  u16*   wqt  = (u16*)(ws + 128 * MB);      // 8 MB: wqt|wkt|wvt|wot contiguous
  float* bcat = (float*)(ws + 136 * MB);    // 12 KB
  u16*   oA   = (u16*)(ws + 137 * MB);      // 32 MB
  u16*   oB   = (u16*)(ws + 169 * MB);      // 32 MB  (end: 201 MB)

  int n4tok = (int)((size_t)NTOK * DM / 4);
  k_convert<<<(n4tok + 255) / 256, 256, 0, stream>>>(x, xb, n4tok);
  k_transpose4<<<dim3(DM / 32, DM / 32, 4), dim3(32, 8), 0, stream>>>(Wq, Wk, Wv, Wo, wqt);
  k_catbias<<<12, 256, 0, stream>>>(bq, bk, bv, bcat);

  // fused QKV GEMM: N=3072 over [wqt|wkt|wvt]; q,k -> qkb row-major; v -> vtb transposed
  k_gemm<<<dim3(3 * DM / 128, NTOK / 128), 256, 0, stream>>>(
      xb, wqt, bcat, nullptr, qkb, 2048, vtb, 2048, NTOK, 3 * DM, DM);

  k_attn<<<512, 256, 0, stream>>>(qkb, vtb, oA, oB);

  int n8tok = (int)((size_t)NTOK * DM / 8);
  k_norm<<<(n8tok + 255) / 256, 256, 0, stream>>>(oA, oB, xb, n8tok);

  u16* wot = wqt + 3 * (size_t)DM * DM;
  k_gemm<<<dim3(DM / 128, NTOK / 128), 256, 0, stream>>>(
      xb, wot, bo, out, nullptr, DM, nullptr, DM, NTOK, DM, DM);
}